// Round 1
// baseline (1154.776 us; speedup 1.0000x reference)
//
#include <hip/hip_runtime.h>
#include <math.h>

#define NB 16
#define NH 256
#define NW 256
#define NCIN 64
#define NCOUT 64
#define REGSZ 16384                  // floats per (b,h) region of d_out
#define TWO_PI 6.28318530717958647692f
#define FSCALE (1.0f/65536.0f)       // norm='forward' 1/(H*W)

// (C + iS) *= (-i)^r   (r compile-time 0..3)
__device__ __forceinline__ void rot_mi(float& C, float& S, int r) {
    if (r == 1) { float t = C; C = S;  S = -t; }
    else if (r == 2) { C = -C; S = -S; }
    else if (r == 3) { float t = C; C = -S; S = t; }
}
// (C + iS) *= (i)^r
__device__ __forceinline__ void rot_pi(float& C, float& S, int r) {
    if (r == 1) { float t = C; C = -S; S = t; }
    else if (r == 2) { C = -C; S = -S; }
    else if (r == 3) { float t = C; C = S;  S = -t; }
}

// ---------------- K1: forward DFT over w (real -> 32 complex modes) ----------
// G1[b,h,ky,i] = (1/65536) * sum_w x[b,h,w,i] e^{-2pi i ky w/256}
// stored interleaved float2 at region(b,h) offset 2*(ky*64+i)
__global__ __launch_bounds__(256) void k1_dft_w(const float* __restrict__ x,
                                                float* __restrict__ O) {
    int bh = blockIdx.x;             // 0..2047, 2 h per block
    int b  = bh >> 7;
    int h0 = (bh & 127) * 2;
    int t  = threadIdx.x;
    int i  = t & 63;
    int kg = t >> 6;                 // 0..3 -> ky base kg*8
    __shared__ float2 tw[256];
    { float s, c; sincosf(TWO_PI * (float)t * (1.0f/256.0f), &s, &c);
      tw[t] = make_float2(c, s); }
    __syncthreads();

    float ar0[8], ai0[8], ar1[8], ai1[8];
#pragma unroll
    for (int jj = 0; jj < 8; ++jj) { ar0[jj]=ai0[jj]=ar1[jj]=ai1[jj]=0.f; }

    const float* xp0 = x + ((b*NH + h0) * NW) * NCIN + i;
    const float* xp1 = xp0 + NW*NCIN;
    int ky0 = kg * 8;

    for (int j = 0; j < 64; ++j) {
        float x0[4], x1[4];
#pragma unroll
        for (int q = 0; q < 4; ++q) {
            x0[q] = xp0[(j + 64*q)*NCIN] * FSCALE;
            x1[q] = xp1[(j + 64*q)*NCIN] * FSCALE;
        }
#pragma unroll
        for (int jj = 0; jj < 8; ++jj) {
            int ky = ky0 + jj;
            int p  = (ky * j) & 255;
            float2 cs = tw[p];
            float C = cs.x, S = -cs.y;   // e^{-i theta}
#pragma unroll
            for (int q = 0; q < 4; ++q) {
                ar0[jj] = fmaf(x0[q], C, ar0[jj]);
                ai0[jj] = fmaf(x0[q], S, ai0[jj]);
                ar1[jj] = fmaf(x1[q], C, ar1[jj]);
                ai1[jj] = fmaf(x1[q], S, ai1[jj]);
                rot_mi(C, S, jj & 3);    // ky&3 == jj&3
            }
        }
    }
    float2* g0 = (float2*)(O + (b*NH + h0)     * REGSZ);
    float2* g1 = (float2*)(O + (b*NH + h0 + 1) * REGSZ);
#pragma unroll
    for (int jj = 0; jj < 8; ++jj) {
        int ky = ky0 + jj;
        g0[ky*64 + i] = make_float2(ar0[jj], ai0[jj]);
        g1[ky*64 + i] = make_float2(ar1[jj], ai1[jj]);
    }
}

// ---------------- K2: forward DFT over h (keep 64 kx modes) ------------------
// X_ft[b,kxidx,ky,i] = sum_h G1[b,h,ky,i] e^{-2pi i kx h/256},
// kx = kxidx<32 ? kxidx : kxidx+192.
// X_ft stored: e=(kxidx*32+ky)*64+i; region b*256+(e>>12), off 4096+2*(e&4095)
__global__ __launch_bounds__(512) void k2_dft_h(float* __restrict__ O) {
    int b  = blockIdx.x >> 5;
    int ky = blockIdx.x & 31;
    int t  = threadIdx.x;
    int i  = t & 63;
    int kg = t >> 6;                 // 0..7
    __shared__ float2 tw[256];
    if (t < 256) { float s, c; sincosf(TWO_PI * (float)t * (1.0f/256.0f), &s, &c);
                   tw[t] = make_float2(c, s); }
    __syncthreads();

    float xr[8], xi[8];
#pragma unroll
    for (int q = 0; q < 8; ++q) { xr[q] = xi[q] = 0.f; }
    int kxb = (kg & 4) ? (kg*8 + 192) : (kg*8);   // 0,8,16,24,224,232,240,248
    const float* base = O + (b*NH)*REGSZ + 2*(ky*64 + i);

    for (int j = 0; j < 64; ++j) {
        float2 g[4];
#pragma unroll
        for (int q = 0; q < 4; ++q)
            g[q] = *(const float2*)(base + (size_t)(j + 64*q)*REGSZ);
#pragma unroll
        for (int qq = 0; qq < 8; ++qq) {
            int kx = kxb + qq;
            int p  = (kx * j) & 255;
            float2 cs = tw[p];
            float C = cs.x, S = -cs.y;
#pragma unroll
            for (int q = 0; q < 4; ++q) {
                xr[qq] = fmaf(g[q].x, C, fmaf(-g[q].y, S, xr[qq]));
                xi[qq] = fmaf(g[q].y, C, fmaf( g[q].x, S, xi[qq]));
                rot_mi(C, S, qq & 3);    // kx&3 == qq&3 (kxb % 4 == 0)
            }
        }
    }
#pragma unroll
    for (int qq = 0; qq < 8; ++qq) {
        int kxidx = kg*8 + qq;
        int e = (kxidx*32 + ky)*64 + i;
        float* p = O + (b*256 + (e >> 12))*REGSZ + 4096 + 2*(e & 4095);
        *(float2*)p = make_float2(xr[qq], xi[qq]);
    }
}

// ---------------- K3: channel mixing (complex 64x64 per (kx,ky)) -------------
__global__ __launch_bounds__(256) void k3_mix(const float* __restrict__ w1re,
                                              const float* __restrict__ w1im,
                                              const float* __restrict__ w2re,
                                              const float* __restrict__ w2im,
                                              float* __restrict__ O) {
    int kxidx = blockIdx.x >> 5;
    int ky    = blockIdx.x & 31;
    int m     = kxidx & 31;
    const float* wre = (kxidx < 32) ? w1re : w2re;
    const float* wim = (kxidx < 32) ? w1im : w2im;
    __shared__ float2 lw[4096];      // [i][o]
    __shared__ float2 lx[1024];      // [b][i]
    int t = threadIdx.x;
    int wofs = m*32 + ky;
    for (int n = t; n < 4096; n += 256) {
        int i = n >> 6, o = n & 63;
        int a = i*65536 + o*1024 + wofs;     // (Cin,Cout,M1,M2) layout
        lw[n] = make_float2(wre[a], wim[a]);
    }
    int ebase = (kxidx*32 + ky)*64;
    for (int n = t; n < 1024; n += 256) {
        int b = n >> 6, i = n & 63;
        int e = ebase + i;
        lx[n] = *(const float2*)(O + (b*256 + (e >> 12))*REGSZ + 4096 + 2*(e & 4095));
    }
    __syncthreads();
    int o = t & 63, bq = t >> 6;
#pragma unroll
    for (int q = 0; q < 4; ++q) {
        int b = bq*4 + q;
        float ar = 0.f, ai = 0.f;
        for (int i = 0; i < 64; ++i) {
            float2 xv = lx[b*64 + i];
            float2 wv = lw[i*64 + o];
            ar = fmaf(xv.x, wv.x, fmaf(-xv.y, wv.y, ar));
            ai = fmaf(xv.x, wv.y, fmaf( xv.y, wv.x, ai));
        }
        int e = ebase + o;
        *(float2*)(O + (b*256 + 32 + (e >> 12))*REGSZ + 4096 + 2*(e & 4095))
            = make_float2(ar, ai);
    }
}

// ---------------- K4: inverse DFT over h ------------------------------------
// tmp[b,h,ky,o] = sum_kxidx out_ft[b,kxidx,ky,o] e^{+2pi i kx h/256}
// tmp stored interleaved at region(b,h) offset 2*(ky*64+o)
__global__ __launch_bounds__(512) void k4_idft_h(float* __restrict__ O) {
    int b  = blockIdx.x >> 5;
    int ky = blockIdx.x & 31;
    int t  = threadIdx.x;
    __shared__ float2 tw[256];
    __shared__ float2 lof[4096];     // [kxidx][o]
    if (t < 256) { float s, c; sincosf(TWO_PI * (float)t * (1.0f/256.0f), &s, &c);
                   tw[t] = make_float2(c, s); }
    for (int n = t; n < 4096; n += 512) {
        int kxidx = n >> 6, o = n & 63;
        int e = (kxidx*32 + ky)*64 + o;
        lof[n] = *(const float2*)(O + (b*256 + 32 + (e >> 12))*REGSZ + 4096 + 2*(e & 4095));
    }
    __syncthreads();
    int o = t & 63, jg = t >> 6;     // jg 0..7
    for (int jj = 0; jj < 8; ++jj) {
        int j = jg*8 + jj;
        float tr[4], ti[4];
#pragma unroll
        for (int q = 0; q < 4; ++q) { tr[q] = ti[q] = 0.f; }
#pragma unroll
        for (int kxidx = 0; kxidx < 64; ++kxidx) {
            int kx = (kxidx < 32) ? kxidx : kxidx + 192;
            int p  = (kx * j) & 255;
            float2 cs = tw[p];
            float2 of = lof[kxidx*64 + o];
            float C = cs.x, S = cs.y;    // e^{+i theta}
#pragma unroll
            for (int q = 0; q < 4; ++q) {
                tr[q] = fmaf(of.x, C, fmaf(-of.y, S, tr[q]));
                ti[q] = fmaf(of.x, S, fmaf( of.y, C, ti[q]));
                rot_pi(C, S, kxidx & 3); // kx&3 == kxidx&3 (192 % 4 == 0)
            }
        }
#pragma unroll
        for (int q = 0; q < 4; ++q) {
            int h = j + 64*q;
            *(float2*)(O + (b*NH + h)*REGSZ + 2*(ky*64 + o))
                = make_float2(tr[q], ti[q]);
        }
    }
}

// ---------------- K5: inverse rfft over w + bias ----------------------------
// out[w] = bias + Re(tmp0) + sum_{ky=1..31} 2 Re(tmp_ky e^{+2pi i ky w/256})
__global__ __launch_bounds__(256) void k5_idft_w(const float* __restrict__ bias,
                                                 float* __restrict__ O) {
    int b = blockIdx.x >> 8;
    int h = blockIdx.x & 255;
    int t = threadIdx.x;
    int o = t & 63, jg = t >> 6;     // jg 0..3
    __shared__ float2 tw[256];
    { float s, c; sincosf(TWO_PI * (float)t * (1.0f/256.0f), &s, &c);
      tw[t] = make_float2(c, s); }
    float* R = O + (b*NH + h)*REGSZ;
    float tr[32], ti[32];
#pragma unroll
    for (int ky = 0; ky < 32; ++ky) {
        float2 v = *(const float2*)(R + 2*(ky*64 + o));
        float sc = (ky == 0) ? 1.f : 2.f;   // Hermitian doubling; bin0 real-only
        tr[ky] = v.x * sc; ti[ky] = v.y * sc;
    }
    float bv = bias[o];
    __syncthreads();                 // all tmp reads done before any overwrite
    for (int jj = 0; jj < 16; ++jj) {
        int j = jg*16 + jj;
        float acc[4] = {bv, bv, bv, bv};
#pragma unroll
        for (int ky = 0; ky < 32; ++ky) {
            int p = (ky * j) & 255;
            float2 cs = tw[p];
            float C = cs.x, S = cs.y;
#pragma unroll
            for (int q = 0; q < 4; ++q) {
                acc[q] = fmaf(tr[ky], C, fmaf(-ti[ky], S, acc[q]));
                rot_pi(C, S, ky & 3);
            }
        }
#pragma unroll
        for (int q = 0; q < 4; ++q) {
            R[(j + 64*q)*64 + o] = acc[q];
        }
    }
}

extern "C" void kernel_launch(void* const* d_in, const int* in_sizes, int n_in,
                              void* d_out, int out_size, void* d_ws, size_t ws_size,
                              hipStream_t stream) {
    (void)in_sizes; (void)n_in; (void)d_ws; (void)ws_size; (void)out_size;
    const float* x    = (const float*)d_in[0];
    const float* w1re = (const float*)d_in[1];
    const float* w1im = (const float*)d_in[2];
    const float* w2re = (const float*)d_in[3];
    const float* w2im = (const float*)d_in[4];
    const float* bias = (const float*)d_in[5];
    float* O = (float*)d_out;

    k1_dft_w<<<2048, 256, 0, stream>>>(x, O);
    k2_dft_h<<<512, 512, 0, stream>>>(O);
    k3_mix  <<<2048, 256, 0, stream>>>(w1re, w1im, w2re, w2im, O);
    k4_idft_h<<<512, 512, 0, stream>>>(O);
    k5_idft_w<<<4096, 256, 0, stream>>>(bias, O);
}

// Round 2
// 545.324 us; speedup vs baseline: 2.1176x; 2.1176x over previous
//
#include <hip/hip_runtime.h>
#include <math.h>

#define NB 16
#define NH 256
#define NW 256
#define NCIN 64
#define NCOUT 64
#define REGSZ 16384                  // floats per (b,h) 64 KB region of d_out
#define TWO_PI 6.28318530717958647692f
#define FSCALE (1.0f/65536.0f)       // norm='forward' 1/(H*W)

// Region byte map (region r = 64 KB slice (b*256+h) of d_out):
//   floats [    0, 4096)  A  = G1[b][h][ky][i]        (written K1, read K2)
//   floats [ 4096, 8192)  B/C slots:
//        regions b*256+[0,64):   X_ft  slot (b,ky,kxhalf)   (K2 -> K3)
//        regions b*256+[64,128): out_ft chunk (b,kx)        (K3 -> K4)
//   floats [ 8192,12288)  W'' chunk (kx,i) at region kx*64+i (K0 -> K3)
//   floats [12288,16384)  D  = tmp[b][h][ky][o]        (K4 -> K5)
// K5 reads only its own region's D, __syncthreads, writes own region [0,16384).

// (C + iS) *= (-i)^r   (r compile-time 0..3)
__device__ __forceinline__ void rot_mi(float& C, float& S, int r) {
    if (r == 1) { float t = C; C = S;  S = -t; }
    else if (r == 2) { C = -C; S = -S; }
    else if (r == 3) { float t = C; C = -S; S = t; }
}
// (C + iS) *= (i)^r
__device__ __forceinline__ void rot_pi(float& C, float& S, int r) {
    if (r == 1) { float t = C; C = -S; S = t; }
    else if (r == 2) { C = -C; S = -S; }
    else if (r == 3) { float t = C; C = S;  S = -t; }
}

// ---------------- K0: weight transpose -> W''[kx][i][ky][o] ------------------
// reads w[i][o][m][ky] (coalesced 128B per lane along m2), writes contiguous.
__global__ __launch_bounds__(256) void k0_wt(const float* __restrict__ w1re,
                                             const float* __restrict__ w1im,
                                             const float* __restrict__ w2re,
                                             const float* __restrict__ w2im,
                                             float* __restrict__ O) {
    int kx = blockIdx.x >> 4;        // 0..63
    int ig = blockIdx.x & 15;        // i-group of 4
    int t  = threadIdx.x;
    int o  = t & 63, isub = t >> 6;
    int i  = ig*4 + isub;
    const float* wre = (kx < 32) ? w1re : w2re;
    const float* wim = (kx < 32) ? w1im : w2im;
    int m = kx & 31;
    const float4* pr = (const float4*)(wre + ((i*64 + o)*32 + m)*32);
    const float4* pi = (const float4*)(wim + ((i*64 + o)*32 + m)*32);
    float re[32], im[32];
#pragma unroll
    for (int q = 0; q < 8; ++q) {
        float4 a = pr[q], b = pi[q];
        re[4*q+0]=a.x; re[4*q+1]=a.y; re[4*q+2]=a.z; re[4*q+3]=a.w;
        im[4*q+0]=b.x; im[4*q+1]=b.y; im[4*q+2]=b.z; im[4*q+3]=b.w;
    }
    float* dst = O + (size_t)(kx*64 + i)*REGSZ + 8192;
#pragma unroll
    for (int ky = 0; ky < 32; ++ky)
        *(float2*)(dst + 2*(ky*64 + o)) = make_float2(re[ky], im[ky]);
}

// ---------------- K1: forward DFT over w (real -> 32 complex modes) ----------
__global__ __launch_bounds__(256) void k1_dft_w(const float* __restrict__ x,
                                                float* __restrict__ O) {
    int bh = blockIdx.x;             // 0..2047, 2 h per block
    int b  = bh >> 7;
    int h0 = (bh & 127) * 2;
    int t  = threadIdx.x;
    int i  = t & 63;
    int kg = t >> 6;                 // 0..3 -> ky base kg*8
    __shared__ float2 tw[256];
    { float s, c; sincosf(TWO_PI * (float)t * (1.0f/256.0f), &s, &c);
      tw[t] = make_float2(c, s); }
    __syncthreads();

    float ar0[8], ai0[8], ar1[8], ai1[8];
#pragma unroll
    for (int jj = 0; jj < 8; ++jj) { ar0[jj]=ai0[jj]=ar1[jj]=ai1[jj]=0.f; }

    const float* xp0 = x + ((b*NH + h0) * NW) * NCIN + i;
    const float* xp1 = xp0 + NW*NCIN;
    int ky0 = kg * 8;

    for (int j = 0; j < 64; ++j) {
        float x0[4], x1[4];
#pragma unroll
        for (int q = 0; q < 4; ++q) {
            x0[q] = xp0[(j + 64*q)*NCIN] * FSCALE;
            x1[q] = xp1[(j + 64*q)*NCIN] * FSCALE;
        }
#pragma unroll
        for (int jj = 0; jj < 8; ++jj) {
            int ky = ky0 + jj;
            int p  = (ky * j) & 255;
            float2 cs = tw[p];
            float C = cs.x, S = -cs.y;   // e^{-i theta}
#pragma unroll
            for (int q = 0; q < 4; ++q) {
                ar0[jj] = fmaf(x0[q], C, ar0[jj]);
                ai0[jj] = fmaf(x0[q], S, ai0[jj]);
                ar1[jj] = fmaf(x1[q], C, ar1[jj]);
                ai1[jj] = fmaf(x1[q], S, ai1[jj]);
                rot_mi(C, S, jj & 3);    // ky&3 == jj&3
            }
        }
    }
    float2* g0 = (float2*)(O + (size_t)(b*NH + h0)     * REGSZ);
    float2* g1 = (float2*)(O + (size_t)(b*NH + h0 + 1) * REGSZ);
#pragma unroll
    for (int jj = 0; jj < 8; ++jj) {
        int ky = ky0 + jj;
        g0[ky*64 + i] = make_float2(ar0[jj], ai0[jj]);
        g1[ky*64 + i] = make_float2(ar1[jj], ai1[jj]);
    }
}

// ---------------- K2: forward DFT over h (keep 64 kx modes) ------------------
// writes X_ft slot: region b*256 + (kx>=32?32:0) + ky, floats 4096 + 2*((kx&31)*64+i)
__global__ __launch_bounds__(512) void k2_dft_h(float* __restrict__ O) {
    int b  = blockIdx.x >> 5;
    int ky = blockIdx.x & 31;
    int t  = threadIdx.x;
    int i  = t & 63;
    int kg = t >> 6;                 // 0..7
    __shared__ float2 tw[256];
    if (t < 256) { float s, c; sincosf(TWO_PI * (float)t * (1.0f/256.0f), &s, &c);
                   tw[t] = make_float2(c, s); }
    __syncthreads();

    float xr[8], xi[8];
#pragma unroll
    for (int q = 0; q < 8; ++q) { xr[q] = xi[q] = 0.f; }
    int kxb = (kg & 4) ? (kg*8 + 192) : (kg*8);   // 0,8,16,24,224,232,240,248
    const float* base = O + (size_t)(b*NH)*REGSZ + 2*(ky*64 + i);

    for (int j = 0; j < 64; ++j) {
        float2 g[4];
#pragma unroll
        for (int q = 0; q < 4; ++q)
            g[q] = *(const float2*)(base + (size_t)(j + 64*q)*REGSZ);
#pragma unroll
        for (int qq = 0; qq < 8; ++qq) {
            int kx = kxb + qq;
            int p  = (kx * j) & 255;
            float2 cs = tw[p];
            float C = cs.x, S = -cs.y;
#pragma unroll
            for (int q = 0; q < 4; ++q) {
                xr[qq] = fmaf(g[q].x, C, fmaf(-g[q].y, S, xr[qq]));
                xi[qq] = fmaf(g[q].y, C, fmaf( g[q].x, S, xi[qq]));
                rot_mi(C, S, qq & 3);    // kx&3 == qq&3 (kxb % 4 == 0)
            }
        }
    }
#pragma unroll
    for (int qq = 0; qq < 8; ++qq) {
        int kxidx = kg*8 + qq;
        int reg = b*256 + ((kxidx >> 5) << 5) + ky;
        float* p = O + (size_t)reg*REGSZ + 4096 + 2*((kxidx & 31)*64 + i);
        *(float2*)p = make_float2(xr[qq], xi[qq]);
    }
}

// ---------------- K3: channel mixing (complex 64x64 per (kx,ky)) -------------
// block (kx,b): stage X[ky][i] in LDS, stream W''[kx][i][ky][o] contiguous.
__global__ __launch_bounds__(512) void k3_mix(float* __restrict__ O) {
    int kx = blockIdx.x >> 4;        // 0..63
    int b  = blockIdx.x & 15;
    int t  = threadIdx.x;
    __shared__ float2 lx[2048];      // [ky][i]
    int koff = (kx >> 5) << 5;
    int klo  = kx & 31;
    for (int n = t; n < 2048; n += 512) {
        int ky = n >> 6, i = n & 63;
        lx[n] = *(const float2*)(O + (size_t)(b*256 + koff + ky)*REGSZ
                                   + 4096 + 2*(klo*64 + i));
    }
    __syncthreads();
    int ky = t >> 4, o0 = (t & 15)*4;
    float ar[4] = {0,0,0,0}, ai[4] = {0,0,0,0};
    for (int i = 0; i < 64; ++i) {
        float2 xv = lx[ky*64 + i];
        const float* wp = O + (size_t)(kx*64 + i)*REGSZ + 8192 + 2*(ky*64 + o0);
        float4 w01 = *(const float4*)(wp);
        float4 w23 = *(const float4*)(wp + 4);
        ar[0] = fmaf(xv.x, w01.x, fmaf(-xv.y, w01.y, ar[0]));
        ai[0] = fmaf(xv.x, w01.y, fmaf( xv.y, w01.x, ai[0]));
        ar[1] = fmaf(xv.x, w01.z, fmaf(-xv.y, w01.w, ar[1]));
        ai[1] = fmaf(xv.x, w01.w, fmaf( xv.y, w01.z, ai[1]));
        ar[2] = fmaf(xv.x, w23.x, fmaf(-xv.y, w23.y, ar[2]));
        ai[2] = fmaf(xv.x, w23.y, fmaf( xv.y, w23.x, ai[2]));
        ar[3] = fmaf(xv.x, w23.z, fmaf(-xv.y, w23.w, ar[3]));
        ai[3] = fmaf(xv.x, w23.w, fmaf( xv.y, w23.z, ai[3]));
    }
    float* cp = O + (size_t)(b*256 + 64 + kx)*REGSZ + 4096 + 2*(ky*64 + o0);
    ((float4*)cp)[0] = make_float4(ar[0], ai[0], ar[1], ai[1]);
    ((float4*)cp)[1] = make_float4(ar[2], ai[2], ar[3], ai[3]);
}

// ---------------- K4: inverse DFT over h ------------------------------------
// block (b, h-tile of 4): loop kx reading contiguous 16 KB out_ft chunks;
// writes tmp contiguous into each (b,h) region at float offset 12288.
__global__ __launch_bounds__(512) void k4_idft_h(float* __restrict__ O) {
    int b  = blockIdx.x >> 6;        // 0..15
    int hg = blockIdx.x & 63;        // h0 = hg*4
    int t  = threadIdx.x;
    __shared__ float2 tw[256];
    if (t < 256) { float s, c; sincosf(TWO_PI * (float)t * (1.0f/256.0f), &s, &c);
                   tw[t] = make_float2(c, s); }
    __syncthreads();
    int p0 = t*4;                    // 4 consecutive (ky,o) pairs
    int h0 = hg*4;
    float tr[4][4], ti[4][4];        // [hh][pair]
#pragma unroll
    for (int hh = 0; hh < 4; ++hh)
#pragma unroll
        for (int p = 0; p < 4; ++p) { tr[hh][p] = 0.f; ti[hh][p] = 0.f; }

    for (int kxi = 0; kxi < 64; ++kxi) {
        int kxe = (kxi < 32) ? kxi : kxi + 192;
        const float* cp = O + (size_t)(b*256 + 64 + kxi)*REGSZ + 4096 + 2*p0;
        float4 c01 = ((const float4*)cp)[0];
        float4 c23 = ((const float4*)cp)[1];
#pragma unroll
        for (int hh = 0; hh < 4; ++hh) {
            float2 cs = tw[(kxe*(h0 + hh)) & 255];   // e^{+i theta}
            tr[hh][0] = fmaf(c01.x, cs.x, fmaf(-c01.y, cs.y, tr[hh][0]));
            ti[hh][0] = fmaf(c01.x, cs.y, fmaf( c01.y, cs.x, ti[hh][0]));
            tr[hh][1] = fmaf(c01.z, cs.x, fmaf(-c01.w, cs.y, tr[hh][1]));
            ti[hh][1] = fmaf(c01.z, cs.y, fmaf( c01.w, cs.x, ti[hh][1]));
            tr[hh][2] = fmaf(c23.x, cs.x, fmaf(-c23.y, cs.y, tr[hh][2]));
            ti[hh][2] = fmaf(c23.x, cs.y, fmaf( c23.y, cs.x, ti[hh][2]));
            tr[hh][3] = fmaf(c23.z, cs.x, fmaf(-c23.w, cs.y, tr[hh][3]));
            ti[hh][3] = fmaf(c23.z, cs.y, fmaf( c23.w, cs.x, ti[hh][3]));
        }
    }
#pragma unroll
    for (int hh = 0; hh < 4; ++hh) {
        float* dp = O + (size_t)(b*256 + h0 + hh)*REGSZ + 12288 + 2*p0;
        ((float4*)dp)[0] = make_float4(tr[hh][0], ti[hh][0], tr[hh][1], ti[hh][1]);
        ((float4*)dp)[1] = make_float4(tr[hh][2], ti[hh][2], tr[hh][3], ti[hh][3]);
    }
}

// ---------------- K5: inverse rfft over w + bias ----------------------------
__global__ __launch_bounds__(256) void k5_idft_w(const float* __restrict__ bias,
                                                 float* __restrict__ O) {
    int b = blockIdx.x >> 8;
    int h = blockIdx.x & 255;
    int t = threadIdx.x;
    int o = t & 63, jg = t >> 6;     // jg 0..3
    __shared__ float2 tw[256];
    { float s, c; sincosf(TWO_PI * (float)t * (1.0f/256.0f), &s, &c);
      tw[t] = make_float2(c, s); }
    float* R = O + (size_t)(b*NH + h)*REGSZ;
    float tr[32], ti[32];
#pragma unroll
    for (int ky = 0; ky < 32; ++ky) {
        float2 v = *(const float2*)(R + 12288 + 2*(ky*64 + o));
        float sc = (ky == 0) ? 1.f : 2.f;   // Hermitian doubling; bin0 real-only
        tr[ky] = v.x * sc; ti[ky] = v.y * sc;
    }
    float bv = bias[o];
    __syncthreads();                 // all tmp reads done before any overwrite
    for (int jj = 0; jj < 16; ++jj) {
        int j = jg*16 + jj;
        float acc[4] = {bv, bv, bv, bv};
#pragma unroll
        for (int ky = 0; ky < 32; ++ky) {
            int p = (ky * j) & 255;
            float2 cs = tw[p];
            float C = cs.x, S = cs.y;
#pragma unroll
            for (int q = 0; q < 4; ++q) {
                acc[q] = fmaf(tr[ky], C, fmaf(-ti[ky], S, acc[q]));
                rot_pi(C, S, ky & 3);
            }
        }
#pragma unroll
        for (int q = 0; q < 4; ++q) {
            R[(j + 64*q)*64 + o] = acc[q];
        }
    }
}

extern "C" void kernel_launch(void* const* d_in, const int* in_sizes, int n_in,
                              void* d_out, int out_size, void* d_ws, size_t ws_size,
                              hipStream_t stream) {
    (void)in_sizes; (void)n_in; (void)d_ws; (void)ws_size; (void)out_size;
    const float* x    = (const float*)d_in[0];
    const float* w1re = (const float*)d_in[1];
    const float* w1im = (const float*)d_in[2];
    const float* w2re = (const float*)d_in[3];
    const float* w2im = (const float*)d_in[4];
    const float* bias = (const float*)d_in[5];
    float* O = (float*)d_out;

    k0_wt    <<<1024, 256, 0, stream>>>(w1re, w1im, w2re, w2im, O);
    k1_dft_w <<<2048, 256, 0, stream>>>(x, O);
    k2_dft_h <<< 512, 512, 0, stream>>>(O);
    k3_mix   <<<1024, 512, 0, stream>>>(O);
    k4_idft_h<<<1024, 512, 0, stream>>>(O);
    k5_idft_w<<<4096, 256, 0, stream>>>(bias, O);
}

// Round 3
// 486.748 us; speedup vs baseline: 2.3724x; 1.1203x over previous
//
#include <hip/hip_runtime.h>
#include <math.h>

#define NB 16
#define NH 256
#define NW 256
#define NCIN 64
#define NCOUT 64
#define REGSZ 16384                  // floats per (b,h) 64 KB region of d_out
#define TWO_PI 6.28318530717958647692f
#define FSCALE (1.0f/65536.0f)       // norm='forward' 1/(H*W)

// Region float map (region r = 64 KB slice (b*256+h) of d_out):
//   [    0, 4096)  G1[b][h][ky][i] interleaved     (K1 -> K2)
//   [ 4096, 8192)  regions b*256+[0,64):  X_ft slot (K2 -> K3)
//                  regions b*256+[64,128): out_ft   (K3 -> K4)
//   [ 8192,12288)  W'' chunk (kx,i) at region kx*64+i (K0 -> K3)
//   [12288,16384)  tmp[b][h][ky][o] interleaved    (K4 -> K5)
// K5: one wave per (b,h): loads all its tmp to regs (register dep forces
// waitcnt before any store), then overwrites own region [0,16384).

// (C + iS) *= (-i)^r   (r compile-time 0..3)
__device__ __forceinline__ void rot_mi(float& C, float& S, int r) {
    if (r == 1) { float t = C; C = S;  S = -t; }
    else if (r == 2) { C = -C; S = -S; }
    else if (r == 3) { float t = C; C = -S; S = t; }
}
// (C + iS) *= (i)^r
__device__ __forceinline__ void rot_pi(float& C, float& S, int r) {
    if (r == 1) { float t = C; C = -S; S = t; }
    else if (r == 2) { C = -C; S = -S; }
    else if (r == 3) { float t = C; C = S;  S = -t; }
}

// ---------------- K0: weight transpose -> W''[kx][i][ky][o] ------------------
__global__ __launch_bounds__(256) void k0_wt(const float* __restrict__ w1re,
                                             const float* __restrict__ w1im,
                                             const float* __restrict__ w2re,
                                             const float* __restrict__ w2im,
                                             float* __restrict__ O) {
    int kx = blockIdx.x >> 4;        // 0..63
    int ig = blockIdx.x & 15;        // i-group of 4
    int t  = threadIdx.x;
    int o  = t & 63, isub = t >> 6;
    int i  = ig*4 + isub;
    const float* wre = (kx < 32) ? w1re : w2re;
    const float* wim = (kx < 32) ? w1im : w2im;
    int m = kx & 31;
    const float4* pr = (const float4*)(wre + ((i*64 + o)*32 + m)*32);
    const float4* pi = (const float4*)(wim + ((i*64 + o)*32 + m)*32);
    float re[32], im[32];
#pragma unroll
    for (int q = 0; q < 8; ++q) {
        float4 a = pr[q], b = pi[q];
        re[4*q+0]=a.x; re[4*q+1]=a.y; re[4*q+2]=a.z; re[4*q+3]=a.w;
        im[4*q+0]=b.x; im[4*q+1]=b.y; im[4*q+2]=b.z; im[4*q+3]=b.w;
    }
    float* dst = O + (size_t)(kx*64 + i)*REGSZ + 8192;
#pragma unroll
    for (int ky = 0; ky < 32; ++ky)
        *(float2*)(dst + 2*(ky*64 + o)) = make_float2(re[ky], im[ky]);
}

// ---------------- K1: forward DFT over w (real -> 32 complex modes) ----------
// One wave per (b,h). lane&31 = channel-pair, lane>>5 = ky-half (16 ky each).
// Conjugate-pair symmetry: X_re = sum s[w] cos, X_im = -sum d[w] sin over
// w=0..127, with quadrant rot folding w=j+64 into the same tw read.
__global__ __launch_bounds__(256) void k1_dft_w(const float* __restrict__ x,
                                                float* __restrict__ O) {
    int t = threadIdx.x;
    int wave = t >> 6, lane = t & 63;
    int i2 = lane & 31;              // channel pair: channels 2*i2, 2*i2+1
    int kh = lane >> 5;              // ky = kh*16 + kk
    int bh = blockIdx.x * 4 + wave;  // 0..4095
    __shared__ float2 tw[256];
    { float s, c; sincosf(TWO_PI * (float)t * (1.0f/256.0f), &s, &c);
      tw[t] = make_float2(c, s); }
    __syncthreads();

    const float* xr = x + (size_t)bh * (NW*NCIN) + 2*i2;
    float re[16][2], im[16][2];
#pragma unroll
    for (int kk = 0; kk < 16; ++kk) {
        re[kk][0]=re[kk][1]=im[kk][0]=im[kk][1]=0.f;
    }

    for (int j = 1; j < 64; ++j) {
        float2 xa = *(const float2*)(xr + j*64);          // w=j
        float2 xb = *(const float2*)(xr + (256-j)*64);    // w=256-j
        float2 xc = *(const float2*)(xr + (64+j)*64);     // w=64+j
        float2 xd = *(const float2*)(xr + (192-j)*64);    // w=192-j
        float a0x = xa.x + xb.x, a0y = xa.y + xb.y;
        float d0x = xa.x - xb.x, d0y = xa.y - xb.y;
        float a1x = xc.x + xd.x, a1y = xc.y + xd.y;
        float d1x = xc.x - xd.x, d1y = xc.y - xd.y;
#pragma unroll
        for (int kk = 0; kk < 16; ++kk) {
            int p = ((kh*16 + kk) * j) & 255;
            float2 cs = tw[p];
            float C = cs.x, S = cs.y;
            // q0: w=j  (cos=C, sin=S)
            re[kk][0] = fmaf(a0x, C, re[kk][0]);
            re[kk][1] = fmaf(a0y, C, re[kk][1]);
            im[kk][0] = fmaf(-d0x, S, im[kk][0]);
            im[kk][1] = fmaf(-d0y, S, im[kk][1]);
            // q1: w=64+j  (cos,sin rotated by ky*pi/2; kk&3 compile-time)
            if ((kk & 3) == 0) {        // cos=C, sin=S
                re[kk][0] = fmaf(a1x, C, re[kk][0]);
                re[kk][1] = fmaf(a1y, C, re[kk][1]);
                im[kk][0] = fmaf(-d1x, S, im[kk][0]);
                im[kk][1] = fmaf(-d1y, S, im[kk][1]);
            } else if ((kk & 3) == 1) { // cos=-S, sin=C
                re[kk][0] = fmaf(-a1x, S, re[kk][0]);
                re[kk][1] = fmaf(-a1y, S, re[kk][1]);
                im[kk][0] = fmaf(-d1x, C, im[kk][0]);
                im[kk][1] = fmaf(-d1y, C, im[kk][1]);
            } else if ((kk & 3) == 2) { // cos=-C, sin=-S
                re[kk][0] = fmaf(-a1x, C, re[kk][0]);
                re[kk][1] = fmaf(-a1y, C, re[kk][1]);
                im[kk][0] = fmaf(d1x, S, im[kk][0]);
                im[kk][1] = fmaf(d1y, S, im[kk][1]);
            } else {                    // cos=S, sin=-C
                re[kk][0] = fmaf(a1x, S, re[kk][0]);
                re[kk][1] = fmaf(a1y, S, re[kk][1]);
                im[kk][0] = fmaf(d1x, C, im[kk][0]);
                im[kk][1] = fmaf(d1y, C, im[kk][1]);
            }
        }
    }
    // edges: w = 0, 64, 128, 192
    float2 e0   = *(const float2*)(xr + 0);
    float2 e64  = *(const float2*)(xr + 64*64);
    float2 e128 = *(const float2*)(xr + 128*64);
    float2 e192 = *(const float2*)(xr + 192*64);
    float a64x = e64.x + e192.x, a64y = e64.y + e192.y;
    float d64x = e64.x - e192.x, d64y = e64.y - e192.y;
#pragma unroll
    for (int kk = 0; kk < 16; ++kk) {
        re[kk][0] += e0.x; re[kk][1] += e0.y;           // w=0 (cos=1,sin=0)
        if (kk & 1) { re[kk][0] -= e128.x; re[kk][1] -= e128.y; }  // w=128
        else        { re[kk][0] += e128.x; re[kk][1] += e128.y; }
        if ((kk & 3) == 0)      { re[kk][0] += a64x; re[kk][1] += a64y; }
        else if ((kk & 3) == 1) { im[kk][0] -= d64x; im[kk][1] -= d64y; }
        else if ((kk & 3) == 2) { re[kk][0] -= a64x; re[kk][1] -= a64y; }
        else                    { im[kk][0] += d64x; im[kk][1] += d64y; }
    }
    float* R = O + (size_t)bh * REGSZ;
#pragma unroll
    for (int kk = 0; kk < 16; ++kk) {
        int ky = kh*16 + kk;
        *(float4*)(R + 2*(ky*64 + 2*i2)) =
            make_float4(re[kk][0]*FSCALE, im[kk][0]*FSCALE,
                        re[kk][1]*FSCALE, im[kk][1]*FSCALE);
    }
}

// ---------------- K2: forward DFT over h (keep 64 kx modes) ------------------
__global__ __launch_bounds__(512) void k2_dft_h(float* __restrict__ O) {
    int b  = blockIdx.x >> 5;
    int ky = blockIdx.x & 31;
    int t  = threadIdx.x;
    int i  = t & 63;
    int kg = t >> 6;                 // 0..7
    __shared__ float2 tw[256];
    if (t < 256) { float s, c; sincosf(TWO_PI * (float)t * (1.0f/256.0f), &s, &c);
                   tw[t] = make_float2(c, s); }
    __syncthreads();

    float xr[8], xi[8];
#pragma unroll
    for (int q = 0; q < 8; ++q) { xr[q] = xi[q] = 0.f; }
    int kxb = (kg & 4) ? (kg*8 + 192) : (kg*8);
    const float* base = O + (size_t)(b*NH)*REGSZ + 2*(ky*64 + i);

    for (int j = 0; j < 64; ++j) {
        float2 g[4];
#pragma unroll
        for (int q = 0; q < 4; ++q)
            g[q] = *(const float2*)(base + (size_t)(j + 64*q)*REGSZ);
#pragma unroll
        for (int qq = 0; qq < 8; ++qq) {
            int kx = kxb + qq;
            int p  = (kx * j) & 255;
            float2 cs = tw[p];
            float C = cs.x, S = -cs.y;
#pragma unroll
            for (int q = 0; q < 4; ++q) {
                xr[qq] = fmaf(g[q].x, C, fmaf(-g[q].y, S, xr[qq]));
                xi[qq] = fmaf(g[q].y, C, fmaf( g[q].x, S, xi[qq]));
                rot_mi(C, S, qq & 3);
            }
        }
    }
#pragma unroll
    for (int qq = 0; qq < 8; ++qq) {
        int kxidx = kg*8 + qq;
        int reg = b*256 + ((kxidx >> 5) << 5) + ky;
        float* p = O + (size_t)reg*REGSZ + 4096 + 2*((kxidx & 31)*64 + i);
        *(float2*)p = make_float2(xr[qq], xi[qq]);
    }
}

// ---------------- K3: channel mixing (complex 64x64 per (kx,ky)) -------------
__global__ __launch_bounds__(512) void k3_mix(float* __restrict__ O) {
    int kx = blockIdx.x >> 4;        // 0..63
    int b  = blockIdx.x & 15;
    int t  = threadIdx.x;
    __shared__ float2 lx[2048];      // [ky][i]
    int koff = (kx >> 5) << 5;
    int klo  = kx & 31;
    for (int n = t; n < 2048; n += 512) {
        int ky = n >> 6, i = n & 63;
        lx[n] = *(const float2*)(O + (size_t)(b*256 + koff + ky)*REGSZ
                                   + 4096 + 2*(klo*64 + i));
    }
    __syncthreads();
    int ky = t >> 4, o0 = (t & 15)*4;
    float ar[4] = {0,0,0,0}, ai[4] = {0,0,0,0};
    for (int i = 0; i < 64; ++i) {
        float2 xv = lx[ky*64 + i];
        const float* wp = O + (size_t)(kx*64 + i)*REGSZ + 8192 + 2*(ky*64 + o0);
        float4 w01 = *(const float4*)(wp);
        float4 w23 = *(const float4*)(wp + 4);
        ar[0] = fmaf(xv.x, w01.x, fmaf(-xv.y, w01.y, ar[0]));
        ai[0] = fmaf(xv.x, w01.y, fmaf( xv.y, w01.x, ai[0]));
        ar[1] = fmaf(xv.x, w01.z, fmaf(-xv.y, w01.w, ar[1]));
        ai[1] = fmaf(xv.x, w01.w, fmaf( xv.y, w01.z, ai[1]));
        ar[2] = fmaf(xv.x, w23.x, fmaf(-xv.y, w23.y, ar[2]));
        ai[2] = fmaf(xv.x, w23.y, fmaf( xv.y, w23.x, ai[2]));
        ar[3] = fmaf(xv.x, w23.z, fmaf(-xv.y, w23.w, ar[3]));
        ai[3] = fmaf(xv.x, w23.w, fmaf( xv.y, w23.z, ai[3]));
    }
    float* cp = O + (size_t)(b*256 + 64 + kx)*REGSZ + 4096 + 2*(ky*64 + o0);
    ((float4*)cp)[0] = make_float4(ar[0], ai[0], ar[1], ai[1]);
    ((float4*)cp)[1] = make_float4(ar[2], ai[2], ar[3], ai[3]);
}

// ---------------- K4: inverse DFT over h ------------------------------------
__global__ __launch_bounds__(512) void k4_idft_h(float* __restrict__ O) {
    int b  = blockIdx.x >> 6;        // 0..15
    int hg = blockIdx.x & 63;        // h0 = hg*4
    int t  = threadIdx.x;
    __shared__ float2 tw[256];
    if (t < 256) { float s, c; sincosf(TWO_PI * (float)t * (1.0f/256.0f), &s, &c);
                   tw[t] = make_float2(c, s); }
    __syncthreads();
    int p0 = t*4;
    int h0 = hg*4;
    float tr[4][4], ti[4][4];
#pragma unroll
    for (int hh = 0; hh < 4; ++hh)
#pragma unroll
        for (int p = 0; p < 4; ++p) { tr[hh][p] = 0.f; ti[hh][p] = 0.f; }

    for (int kxi = 0; kxi < 64; ++kxi) {
        int kxe = (kxi < 32) ? kxi : kxi + 192;
        const float* cp = O + (size_t)(b*256 + 64 + kxi)*REGSZ + 4096 + 2*p0;
        float4 c01 = ((const float4*)cp)[0];
        float4 c23 = ((const float4*)cp)[1];
#pragma unroll
        for (int hh = 0; hh < 4; ++hh) {
            float2 cs = tw[(kxe*(h0 + hh)) & 255];
            tr[hh][0] = fmaf(c01.x, cs.x, fmaf(-c01.y, cs.y, tr[hh][0]));
            ti[hh][0] = fmaf(c01.x, cs.y, fmaf( c01.y, cs.x, ti[hh][0]));
            tr[hh][1] = fmaf(c01.z, cs.x, fmaf(-c01.w, cs.y, tr[hh][1]));
            ti[hh][1] = fmaf(c01.z, cs.y, fmaf( c01.w, cs.x, ti[hh][1]));
            tr[hh][2] = fmaf(c23.x, cs.x, fmaf(-c23.y, cs.y, tr[hh][2]));
            ti[hh][2] = fmaf(c23.x, cs.y, fmaf( c23.y, cs.x, ti[hh][2]));
            tr[hh][3] = fmaf(c23.z, cs.x, fmaf(-c23.w, cs.y, tr[hh][3]));
            ti[hh][3] = fmaf(c23.z, cs.y, fmaf( c23.w, cs.x, ti[hh][3]));
        }
    }
#pragma unroll
    for (int hh = 0; hh < 4; ++hh) {
        float* dp = O + (size_t)(b*256 + h0 + hh)*REGSZ + 12288 + 2*p0;
        ((float4*)dp)[0] = make_float4(tr[hh][0], ti[hh][0], tr[hh][1], ti[hh][1]);
        ((float4*)dp)[1] = make_float4(tr[hh][2], ti[hh][2], tr[hh][3], ti[hh][3]);
    }
}

// ---------------- K5: inverse rfft over w + bias ----------------------------
// One wave per (b,h). lane&31 = o-pair, lane>>5 = ky-half. Output-pair
// symmetry: out[j]=E0-Od0, out[256-j]=E0+Od0, out[64+j]=E1-Od1,
// out[192-j]=E1+Od1; cross-half reduce via shfl_xor(32).
__global__ __launch_bounds__(256) void k5_idft_w(const float* __restrict__ bias,
                                                 float* __restrict__ O) {
    int t = threadIdx.x;
    int wave = t >> 6, lane = t & 63;
    int o2 = lane & 31;              // channels 2*o2, 2*o2+1
    int kh = lane >> 5;
    int bh = blockIdx.x * 4 + wave;
    __shared__ float2 tw[256];
    { float s, c; sincosf(TWO_PI * (float)t * (1.0f/256.0f), &s, &c);
      tw[t] = make_float2(c, s); }
    __syncthreads();

    float* R = O + (size_t)bh * REGSZ;
    float2 bv = *(const float2*)(bias + 2*o2);
    float trr[16][2], tii[16][2];
#pragma unroll
    for (int kk = 0; kk < 16; ++kk) {
        int ky = kh*16 + kk;
        float4 v = *(const float4*)(R + 12288 + 2*(ky*64 + 2*o2));
        float sc = 2.f;
        if (kk == 0) sc = (kh == 0) ? 1.f : 2.f;   // ky=0: no Hermitian double
        trr[kk][0] = v.x*sc; tii[kk][0] = v.y*sc;
        trr[kk][1] = v.z*sc; tii[kk][1] = v.w*sc;
    }
    // edge partial sums (rows 0,64,128,192); register dep on all loads above
    float A[2]={0,0}, Bc[2]={0,0}, P1[2]={0,0}, P2[2]={0,0};
#pragma unroll
    for (int kk = 0; kk < 16; ++kk) {
#pragma unroll
        for (int c = 0; c < 2; ++c) {
            A[c] += trr[kk][c];
            Bc[c] += (kk & 1) ? -trr[kk][c] : trr[kk][c];
            if ((kk & 3) == 0) P1[c] += trr[kk][c];
            else if ((kk & 3) == 2) P1[c] -= trr[kk][c];
            else if ((kk & 3) == 1) P2[c] += tii[kk][c];
            else P2[c] -= tii[kk][c];
        }
    }
#pragma unroll
    for (int c = 0; c < 2; ++c) {
        A[c]  += __shfl_xor(A[c], 32, 64);
        Bc[c] += __shfl_xor(Bc[c], 32, 64);
        P1[c] += __shfl_xor(P1[c], 32, 64);
        P2[c] += __shfl_xor(P2[c], 32, 64);
    }
    if (kh == 0) {
        *(float2*)(R + 0*64   + 2*o2) = make_float2(bv.x + A[0],  bv.y + A[1]);
        *(float2*)(R + 64*64  + 2*o2) = make_float2(bv.x + P1[0] - P2[0],
                                                    bv.y + P1[1] - P2[1]);
    } else {
        *(float2*)(R + 128*64 + 2*o2) = make_float2(bv.x + Bc[0], bv.y + Bc[1]);
        *(float2*)(R + 192*64 + 2*o2) = make_float2(bv.x + P1[0] + P2[0],
                                                    bv.y + P1[1] + P2[1]);
    }

    for (int j = 1; j < 64; ++j) {
        float E0[2]={0,0}, Od0[2]={0,0}, E1[2]={0,0}, Od1[2]={0,0};
#pragma unroll
        for (int kk = 0; kk < 16; ++kk) {
            int p = ((kh*16 + kk) * j) & 255;
            float2 cs = tw[p];
            float C = cs.x, S = cs.y;
            // q0: w=j
            E0[0] = fmaf(trr[kk][0], C, E0[0]);
            E0[1] = fmaf(trr[kk][1], C, E0[1]);
            Od0[0] = fmaf(tii[kk][0], S, Od0[0]);
            Od0[1] = fmaf(tii[kk][1], S, Od0[1]);
            // q1: w=64+j (rot by ky*pi/2)
            if ((kk & 3) == 0) {        // cos=C, sin=S
                E1[0] = fmaf(trr[kk][0], C, E1[0]);
                E1[1] = fmaf(trr[kk][1], C, E1[1]);
                Od1[0] = fmaf(tii[kk][0], S, Od1[0]);
                Od1[1] = fmaf(tii[kk][1], S, Od1[1]);
            } else if ((kk & 3) == 1) { // cos=-S, sin=C
                E1[0] = fmaf(-trr[kk][0], S, E1[0]);
                E1[1] = fmaf(-trr[kk][1], S, E1[1]);
                Od1[0] = fmaf(tii[kk][0], C, Od1[0]);
                Od1[1] = fmaf(tii[kk][1], C, Od1[1]);
            } else if ((kk & 3) == 2) { // cos=-C, sin=-S
                E1[0] = fmaf(-trr[kk][0], C, E1[0]);
                E1[1] = fmaf(-trr[kk][1], C, E1[1]);
                Od1[0] = fmaf(-tii[kk][0], S, Od1[0]);
                Od1[1] = fmaf(-tii[kk][1], S, Od1[1]);
            } else {                    // cos=S, sin=-C
                E1[0] = fmaf(trr[kk][0], S, E1[0]);
                E1[1] = fmaf(trr[kk][1], S, E1[1]);
                Od1[0] = fmaf(-tii[kk][0], C, Od1[0]);
                Od1[1] = fmaf(-tii[kk][1], C, Od1[1]);
            }
        }
#pragma unroll
        for (int c = 0; c < 2; ++c) {
            E0[c]  += __shfl_xor(E0[c], 32, 64);
            Od0[c] += __shfl_xor(Od0[c], 32, 64);
            E1[c]  += __shfl_xor(E1[c], 32, 64);
            Od1[c] += __shfl_xor(Od1[c], 32, 64);
        }
        if (kh == 0) {
            *(float2*)(R + j*64 + 2*o2) =
                make_float2(bv.x + E0[0] - Od0[0], bv.y + E0[1] - Od0[1]);
            *(float2*)(R + (64+j)*64 + 2*o2) =
                make_float2(bv.x + E1[0] - Od1[0], bv.y + E1[1] - Od1[1]);
        } else {
            *(float2*)(R + (256-j)*64 + 2*o2) =
                make_float2(bv.x + E0[0] + Od0[0], bv.y + E0[1] + Od0[1]);
            *(float2*)(R + (192-j)*64 + 2*o2) =
                make_float2(bv.x + E1[0] + Od1[0], bv.y + E1[1] + Od1[1]);
        }
    }
}

extern "C" void kernel_launch(void* const* d_in, const int* in_sizes, int n_in,
                              void* d_out, int out_size, void* d_ws, size_t ws_size,
                              hipStream_t stream) {
    (void)in_sizes; (void)n_in; (void)d_ws; (void)ws_size; (void)out_size;
    const float* x    = (const float*)d_in[0];
    const float* w1re = (const float*)d_in[1];
    const float* w1im = (const float*)d_in[2];
    const float* w2re = (const float*)d_in[3];
    const float* w2im = (const float*)d_in[4];
    const float* bias = (const float*)d_in[5];
    float* O = (float*)d_out;

    k0_wt    <<<1024, 256, 0, stream>>>(w1re, w1im, w2re, w2im, O);
    k1_dft_w <<<1024, 256, 0, stream>>>(x, O);
    k2_dft_h <<< 512, 512, 0, stream>>>(O);
    k3_mix   <<<1024, 512, 0, stream>>>(O);
    k4_idft_h<<<1024, 512, 0, stream>>>(O);
    k5_idft_w<<<1024, 256, 0, stream>>>(bias, O);
}

// Round 4
// 432.513 us; speedup vs baseline: 2.6699x; 1.1254x over previous
//
#include <hip/hip_runtime.h>
#include <math.h>

#define NB 16
#define NH 256
#define NW 256
#define NCIN 64
#define NCOUT 64
#define REGSZ 16384                  // floats per (b,h) 64 KB region of d_out
#define TWO_PI 6.28318530717958647692f
#define FSCALE (1.0f/65536.0f)       // norm='forward' 1/(H*W)

// Region float map (region r = 64 KB slice (b*256+h) of d_out):
//   [    0, 4096)  G1[b][h][ky][i] interleaved     (K1 -> K2)
//   [ 4096, 8192)  regions b*256+[0,64):  X_ft slot (K2 -> K3)
//                  regions b*256+[64,128): out_ft   (K3 -> K4)
//   [ 8192,12288)  W'' chunk (kx,i) at region kx*64+i (K0 -> K3)
//   [12288,16384)  tmp[b][h][ky][o] interleaved    (K4 -> K5)
// K5: one wave per (b,h): loads all its tmp to regs (register dep forces
// waitcnt before any store), then overwrites own region [0,16384).

// (C + iS) *= (-i)^r   (r compile-time 0..3)
__device__ __forceinline__ void rot_mi(float& C, float& S, int r) {
    if (r == 1) { float t = C; C = S;  S = -t; }
    else if (r == 2) { C = -C; S = -S; }
    else if (r == 3) { float t = C; C = -S; S = t; }
}
// (C + iS) *= (i)^r
__device__ __forceinline__ void rot_pi(float& C, float& S, int r) {
    if (r == 1) { float t = C; C = -S; S = t; }
    else if (r == 2) { C = -C; S = -S; }
    else if (r == 3) { float t = C; C = S;  S = -t; }
}

// ---------------- K0: weight transpose -> W''[kx][i][ky][o] ------------------
__global__ __launch_bounds__(256) void k0_wt(const float* __restrict__ w1re,
                                             const float* __restrict__ w1im,
                                             const float* __restrict__ w2re,
                                             const float* __restrict__ w2im,
                                             float* __restrict__ O) {
    int kx = blockIdx.x >> 4;        // 0..63
    int ig = blockIdx.x & 15;        // i-group of 4
    int t  = threadIdx.x;
    int o  = t & 63, isub = t >> 6;
    int i  = ig*4 + isub;
    const float* wre = (kx < 32) ? w1re : w2re;
    const float* wim = (kx < 32) ? w1im : w2im;
    int m = kx & 31;
    const float4* pr = (const float4*)(wre + ((i*64 + o)*32 + m)*32);
    const float4* pi = (const float4*)(wim + ((i*64 + o)*32 + m)*32);
    float re[32], im[32];
#pragma unroll
    for (int q = 0; q < 8; ++q) {
        float4 a = pr[q], b = pi[q];
        re[4*q+0]=a.x; re[4*q+1]=a.y; re[4*q+2]=a.z; re[4*q+3]=a.w;
        im[4*q+0]=b.x; im[4*q+1]=b.y; im[4*q+2]=b.z; im[4*q+3]=b.w;
    }
    float* dst = O + (size_t)(kx*64 + i)*REGSZ + 8192;
#pragma unroll
    for (int ky = 0; ky < 32; ++ky)
        *(float2*)(dst + 2*(ky*64 + o)) = make_float2(re[ky], im[ky]);
}

// ---------------- K1: forward DFT over w (real -> 32 complex modes) ----------
__global__ __launch_bounds__(256) void k1_dft_w(const float* __restrict__ x,
                                                float* __restrict__ O) {
    int t = threadIdx.x;
    int wave = t >> 6, lane = t & 63;
    int i2 = lane & 31;              // channel pair: channels 2*i2, 2*i2+1
    int kh = lane >> 5;              // ky = kh*16 + kk
    int bh = blockIdx.x * 4 + wave;  // 0..4095
    __shared__ float2 tw[256];
    { float s, c; sincosf(TWO_PI * (float)t * (1.0f/256.0f), &s, &c);
      tw[t] = make_float2(c, s); }
    __syncthreads();

    const float* xr = x + (size_t)bh * (NW*NCIN) + 2*i2;
    float re[16][2], im[16][2];
#pragma unroll
    for (int kk = 0; kk < 16; ++kk) {
        re[kk][0]=re[kk][1]=im[kk][0]=im[kk][1]=0.f;
    }

    for (int j = 1; j < 64; ++j) {
        float2 xa = *(const float2*)(xr + j*64);          // w=j
        float2 xb = *(const float2*)(xr + (256-j)*64);    // w=256-j
        float2 xc = *(const float2*)(xr + (64+j)*64);     // w=64+j
        float2 xd = *(const float2*)(xr + (192-j)*64);    // w=192-j
        float a0x = xa.x + xb.x, a0y = xa.y + xb.y;
        float d0x = xa.x - xb.x, d0y = xa.y - xb.y;
        float a1x = xc.x + xd.x, a1y = xc.y + xd.y;
        float d1x = xc.x - xd.x, d1y = xc.y - xd.y;
#pragma unroll
        for (int kk = 0; kk < 16; ++kk) {
            int p = ((kh*16 + kk) * j) & 255;
            float2 cs = tw[p];
            float C = cs.x, S = cs.y;
            re[kk][0] = fmaf(a0x, C, re[kk][0]);
            re[kk][1] = fmaf(a0y, C, re[kk][1]);
            im[kk][0] = fmaf(-d0x, S, im[kk][0]);
            im[kk][1] = fmaf(-d0y, S, im[kk][1]);
            if ((kk & 3) == 0) {        // cos=C, sin=S
                re[kk][0] = fmaf(a1x, C, re[kk][0]);
                re[kk][1] = fmaf(a1y, C, re[kk][1]);
                im[kk][0] = fmaf(-d1x, S, im[kk][0]);
                im[kk][1] = fmaf(-d1y, S, im[kk][1]);
            } else if ((kk & 3) == 1) { // cos=-S, sin=C
                re[kk][0] = fmaf(-a1x, S, re[kk][0]);
                re[kk][1] = fmaf(-a1y, S, re[kk][1]);
                im[kk][0] = fmaf(-d1x, C, im[kk][0]);
                im[kk][1] = fmaf(-d1y, C, im[kk][1]);
            } else if ((kk & 3) == 2) { // cos=-C, sin=-S
                re[kk][0] = fmaf(-a1x, C, re[kk][0]);
                re[kk][1] = fmaf(-a1y, C, re[kk][1]);
                im[kk][0] = fmaf(d1x, S, im[kk][0]);
                im[kk][1] = fmaf(d1y, S, im[kk][1]);
            } else {                    // cos=S, sin=-C
                re[kk][0] = fmaf(a1x, S, re[kk][0]);
                re[kk][1] = fmaf(a1y, S, re[kk][1]);
                im[kk][0] = fmaf(d1x, C, im[kk][0]);
                im[kk][1] = fmaf(d1y, C, im[kk][1]);
            }
        }
    }
    float2 e0   = *(const float2*)(xr + 0);
    float2 e64  = *(const float2*)(xr + 64*64);
    float2 e128 = *(const float2*)(xr + 128*64);
    float2 e192 = *(const float2*)(xr + 192*64);
    float a64x = e64.x + e192.x, a64y = e64.y + e192.y;
    float d64x = e64.x - e192.x, d64y = e64.y - e192.y;
#pragma unroll
    for (int kk = 0; kk < 16; ++kk) {
        re[kk][0] += e0.x; re[kk][1] += e0.y;
        if (kk & 1) { re[kk][0] -= e128.x; re[kk][1] -= e128.y; }
        else        { re[kk][0] += e128.x; re[kk][1] += e128.y; }
        if ((kk & 3) == 0)      { re[kk][0] += a64x; re[kk][1] += a64y; }
        else if ((kk & 3) == 1) { im[kk][0] -= d64x; im[kk][1] -= d64y; }
        else if ((kk & 3) == 2) { re[kk][0] -= a64x; re[kk][1] -= a64y; }
        else                    { im[kk][0] += d64x; im[kk][1] += d64y; }
    }
    float* R = O + (size_t)bh * REGSZ;
#pragma unroll
    for (int kk = 0; kk < 16; ++kk) {
        int ky = kh*16 + kk;
        *(float4*)(R + 2*(ky*64 + 2*i2)) =
            make_float4(re[kk][0]*FSCALE, im[kk][0]*FSCALE,
                        re[kk][1]*FSCALE, im[kk][1]*FSCALE);
    }
}

// ---------------- K2: forward DFT over h (keep 64 kx modes) ------------------
__global__ __launch_bounds__(512) void k2_dft_h(float* __restrict__ O) {
    int b  = blockIdx.x >> 5;
    int ky = blockIdx.x & 31;
    int t  = threadIdx.x;
    int i  = t & 63;
    int kg = t >> 6;                 // 0..7
    __shared__ float2 tw[256];
    if (t < 256) { float s, c; sincosf(TWO_PI * (float)t * (1.0f/256.0f), &s, &c);
                   tw[t] = make_float2(c, s); }
    __syncthreads();

    float xr[8], xi[8];
#pragma unroll
    for (int q = 0; q < 8; ++q) { xr[q] = xi[q] = 0.f; }
    int kxb = (kg & 4) ? (kg*8 + 192) : (kg*8);
    const float* base = O + (size_t)(b*NH)*REGSZ + 2*(ky*64 + i);

    for (int j = 0; j < 64; ++j) {
        float2 g[4];
#pragma unroll
        for (int q = 0; q < 4; ++q)
            g[q] = *(const float2*)(base + (size_t)(j + 64*q)*REGSZ);
#pragma unroll
        for (int qq = 0; qq < 8; ++qq) {
            int kx = kxb + qq;
            int p  = (kx * j) & 255;
            float2 cs = tw[p];
            float C = cs.x, S = -cs.y;
#pragma unroll
            for (int q = 0; q < 4; ++q) {
                xr[qq] = fmaf(g[q].x, C, fmaf(-g[q].y, S, xr[qq]));
                xi[qq] = fmaf(g[q].y, C, fmaf( g[q].x, S, xi[qq]));
                rot_mi(C, S, qq & 3);
            }
        }
    }
#pragma unroll
    for (int qq = 0; qq < 8; ++qq) {
        int kxidx = kg*8 + qq;
        int reg = b*256 + ((kxidx >> 5) << 5) + ky;
        float* p = O + (size_t)reg*REGSZ + 4096 + 2*((kxidx & 31)*64 + i);
        *(float2*)p = make_float2(xr[qq], xi[qq]);
    }
}

// ---------------- K3: channel mixing (complex 64x64 per (kx,ky)) -------------
// block = (kx, ky-quad of 8): stage X for ALL 16 batches in LDS; stream
// W''[kx][i][ky][o] exactly once; accumulate 16 batches in registers.
__global__ __launch_bounds__(512) void k3_mix(float* __restrict__ O) {
    int kx  = blockIdx.x >> 2;       // 0..63
    int kyq = blockIdx.x & 3;        // ky = kyq*8 + (0..7)
    int t   = threadIdx.x;
    __shared__ float2 lx[8192];      // [b][ky8][i] = 64 KB
    int koff = (kx >> 5) << 5;
    int klo  = kx & 31;
    for (int n = t; n < 8192; n += 512) {
        int b = n >> 9, ky8 = (n >> 6) & 7, i = n & 63;
        lx[n] = *(const float2*)(O + (size_t)(b*256 + koff + kyq*8 + ky8)*REGSZ
                                   + 4096 + 2*(klo*64 + i));
    }
    __syncthreads();
    int kyl = t >> 6;                // wave index = local ky
    int o   = t & 63;
    int kyg = kyq*8 + kyl;
    float ar[16], ai[16];
#pragma unroll
    for (int b = 0; b < 16; ++b) { ar[b] = 0.f; ai[b] = 0.f; }
    const float* wbase = O + 8192 + 2*(kyg*64 + o);
    for (int i = 0; i < 64; ++i) {
        float2 wv = *(const float2*)(wbase + (size_t)(kx*64 + i)*REGSZ);
#pragma unroll
        for (int b = 0; b < 16; ++b) {
            float2 xv = lx[(b*8 + kyl)*64 + i];   // broadcast within wave
            ar[b] = fmaf(xv.x, wv.x, fmaf(-xv.y, wv.y, ar[b]));
            ai[b] = fmaf(xv.x, wv.y, fmaf( xv.y, wv.x, ai[b]));
        }
    }
#pragma unroll
    for (int b = 0; b < 16; ++b) {
        float* cp = O + (size_t)(b*256 + 64 + kx)*REGSZ + 4096 + 2*(kyg*64 + o);
        *(float2*)cp = make_float2(ar[b], ai[b]);
    }
}

// ---------------- K4: inverse DFT over h ------------------------------------
// block = (b, h-tile of 16): out_ft[b] (1 MB) read once per block -> total
// L2/L3 traffic 268 MB (was 1 GB). Writes tmp contiguous per h at 12288.
__global__ __launch_bounds__(512) void k4_idft_h(float* __restrict__ O) {
    int b  = blockIdx.x >> 4;        // 0..15
    int hg = blockIdx.x & 15;        // h0 = hg*16
    int t  = threadIdx.x;
    __shared__ float2 tw[256];
    if (t < 256) { float s, c; sincosf(TWO_PI * (float)t * (1.0f/256.0f), &s, &c);
                   tw[t] = make_float2(c, s); }
    __syncthreads();
    int p0 = t*4;                    // 4 consecutive (ky,o) pairs
    int h0 = hg*16;
    float tr[16][4], ti[16][4];
#pragma unroll
    for (int hh = 0; hh < 16; ++hh)
#pragma unroll
        for (int p = 0; p < 4; ++p) { tr[hh][p] = 0.f; ti[hh][p] = 0.f; }

    for (int kxi = 0; kxi < 64; ++kxi) {
        int kxe = (kxi < 32) ? kxi : kxi + 192;
        const float* cp = O + (size_t)(b*256 + 64 + kxi)*REGSZ + 4096 + 2*p0;
        float4 c01 = ((const float4*)cp)[0];
        float4 c23 = ((const float4*)cp)[1];
#pragma unroll
        for (int hh = 0; hh < 16; ++hh) {
            float2 cs = tw[(kxe*(h0 + hh)) & 255];   // e^{+i theta}
            tr[hh][0] = fmaf(c01.x, cs.x, fmaf(-c01.y, cs.y, tr[hh][0]));
            ti[hh][0] = fmaf(c01.x, cs.y, fmaf( c01.y, cs.x, ti[hh][0]));
            tr[hh][1] = fmaf(c01.z, cs.x, fmaf(-c01.w, cs.y, tr[hh][1]));
            ti[hh][1] = fmaf(c01.z, cs.y, fmaf( c01.w, cs.x, ti[hh][1]));
            tr[hh][2] = fmaf(c23.x, cs.x, fmaf(-c23.y, cs.y, tr[hh][2]));
            ti[hh][2] = fmaf(c23.x, cs.y, fmaf( c23.y, cs.x, ti[hh][2]));
            tr[hh][3] = fmaf(c23.z, cs.x, fmaf(-c23.w, cs.y, tr[hh][3]));
            ti[hh][3] = fmaf(c23.z, cs.y, fmaf( c23.w, cs.x, ti[hh][3]));
        }
    }
#pragma unroll
    for (int hh = 0; hh < 16; ++hh) {
        float* dp = O + (size_t)(b*256 + h0 + hh)*REGSZ + 12288 + 2*p0;
        ((float4*)dp)[0] = make_float4(tr[hh][0], ti[hh][0], tr[hh][1], ti[hh][1]);
        ((float4*)dp)[1] = make_float4(tr[hh][2], ti[hh][2], tr[hh][3], ti[hh][3]);
    }
}

// ---------------- K5: inverse rfft over w + bias ----------------------------
__global__ __launch_bounds__(256) void k5_idft_w(const float* __restrict__ bias,
                                                 float* __restrict__ O) {
    int t = threadIdx.x;
    int wave = t >> 6, lane = t & 63;
    int o2 = lane & 31;              // channels 2*o2, 2*o2+1
    int kh = lane >> 5;
    int bh = blockIdx.x * 4 + wave;
    __shared__ float2 tw[256];
    { float s, c; sincosf(TWO_PI * (float)t * (1.0f/256.0f), &s, &c);
      tw[t] = make_float2(c, s); }
    __syncthreads();

    float* R = O + (size_t)bh * REGSZ;
    float2 bv = *(const float2*)(bias + 2*o2);
    float trr[16][2], tii[16][2];
#pragma unroll
    for (int kk = 0; kk < 16; ++kk) {
        int ky = kh*16 + kk;
        float4 v = *(const float4*)(R + 12288 + 2*(ky*64 + 2*o2));
        float sc = 2.f;
        if (kk == 0) sc = (kh == 0) ? 1.f : 2.f;
        trr[kk][0] = v.x*sc; tii[kk][0] = v.y*sc;
        trr[kk][1] = v.z*sc; tii[kk][1] = v.w*sc;
    }
    float A[2]={0,0}, Bc[2]={0,0}, P1[2]={0,0}, P2[2]={0,0};
#pragma unroll
    for (int kk = 0; kk < 16; ++kk) {
#pragma unroll
        for (int c = 0; c < 2; ++c) {
            A[c] += trr[kk][c];
            Bc[c] += (kk & 1) ? -trr[kk][c] : trr[kk][c];
            if ((kk & 3) == 0) P1[c] += trr[kk][c];
            else if ((kk & 3) == 2) P1[c] -= trr[kk][c];
            else if ((kk & 3) == 1) P2[c] += tii[kk][c];
            else P2[c] -= tii[kk][c];
        }
    }
#pragma unroll
    for (int c = 0; c < 2; ++c) {
        A[c]  += __shfl_xor(A[c], 32, 64);
        Bc[c] += __shfl_xor(Bc[c], 32, 64);
        P1[c] += __shfl_xor(P1[c], 32, 64);
        P2[c] += __shfl_xor(P2[c], 32, 64);
    }
    if (kh == 0) {
        *(float2*)(R + 0*64   + 2*o2) = make_float2(bv.x + A[0],  bv.y + A[1]);
        *(float2*)(R + 64*64  + 2*o2) = make_float2(bv.x + P1[0] - P2[0],
                                                    bv.y + P1[1] - P2[1]);
    } else {
        *(float2*)(R + 128*64 + 2*o2) = make_float2(bv.x + Bc[0], bv.y + Bc[1]);
        *(float2*)(R + 192*64 + 2*o2) = make_float2(bv.x + P1[0] + P2[0],
                                                    bv.y + P1[1] + P2[1]);
    }

    for (int j = 1; j < 64; ++j) {
        float E0[2]={0,0}, Od0[2]={0,0}, E1[2]={0,0}, Od1[2]={0,0};
#pragma unroll
        for (int kk = 0; kk < 16; ++kk) {
            int p = ((kh*16 + kk) * j) & 255;
            float2 cs = tw[p];
            float C = cs.x, S = cs.y;
            E0[0] = fmaf(trr[kk][0], C, E0[0]);
            E0[1] = fmaf(trr[kk][1], C, E0[1]);
            Od0[0] = fmaf(tii[kk][0], S, Od0[0]);
            Od0[1] = fmaf(tii[kk][1], S, Od0[1]);
            if ((kk & 3) == 0) {        // cos=C, sin=S
                E1[0] = fmaf(trr[kk][0], C, E1[0]);
                E1[1] = fmaf(trr[kk][1], C, E1[1]);
                Od1[0] = fmaf(tii[kk][0], S, Od1[0]);
                Od1[1] = fmaf(tii[kk][1], S, Od1[1]);
            } else if ((kk & 3) == 1) { // cos=-S, sin=C
                E1[0] = fmaf(-trr[kk][0], S, E1[0]);
                E1[1] = fmaf(-trr[kk][1], S, E1[1]);
                Od1[0] = fmaf(tii[kk][0], C, Od1[0]);
                Od1[1] = fmaf(tii[kk][1], C, Od1[1]);
            } else if ((kk & 3) == 2) { // cos=-C, sin=-S
                E1[0] = fmaf(-trr[kk][0], C, E1[0]);
                E1[1] = fmaf(-trr[kk][1], C, E1[1]);
                Od1[0] = fmaf(-tii[kk][0], S, Od1[0]);
                Od1[1] = fmaf(-tii[kk][1], S, Od1[1]);
            } else {                    // cos=S, sin=-C
                E1[0] = fmaf(trr[kk][0], S, E1[0]);
                E1[1] = fmaf(trr[kk][1], S, E1[1]);
                Od1[0] = fmaf(-tii[kk][0], C, Od1[0]);
                Od1[1] = fmaf(-tii[kk][1], C, Od1[1]);
            }
        }
#pragma unroll
        for (int c = 0; c < 2; ++c) {
            E0[c]  += __shfl_xor(E0[c], 32, 64);
            Od0[c] += __shfl_xor(Od0[c], 32, 64);
            E1[c]  += __shfl_xor(E1[c], 32, 64);
            Od1[c] += __shfl_xor(Od1[c], 32, 64);
        }
        if (kh == 0) {
            *(float2*)(R + j*64 + 2*o2) =
                make_float2(bv.x + E0[0] - Od0[0], bv.y + E0[1] - Od0[1]);
            *(float2*)(R + (64+j)*64 + 2*o2) =
                make_float2(bv.x + E1[0] - Od1[0], bv.y + E1[1] - Od1[1]);
        } else {
            *(float2*)(R + (256-j)*64 + 2*o2) =
                make_float2(bv.x + E0[0] + Od0[0], bv.y + E0[1] + Od0[1]);
            *(float2*)(R + (192-j)*64 + 2*o2) =
                make_float2(bv.x + E1[0] + Od1[0], bv.y + E1[1] + Od1[1]);
        }
    }
}

extern "C" void kernel_launch(void* const* d_in, const int* in_sizes, int n_in,
                              void* d_out, int out_size, void* d_ws, size_t ws_size,
                              hipStream_t stream) {
    (void)in_sizes; (void)n_in; (void)d_ws; (void)ws_size; (void)out_size;
    const float* x    = (const float*)d_in[0];
    const float* w1re = (const float*)d_in[1];
    const float* w1im = (const float*)d_in[2];
    const float* w2re = (const float*)d_in[3];
    const float* w2im = (const float*)d_in[4];
    const float* bias = (const float*)d_in[5];
    float* O = (float*)d_out;

    k0_wt    <<<1024, 256, 0, stream>>>(w1re, w1im, w2re, w2im, O);
    k1_dft_w <<<1024, 256, 0, stream>>>(x, O);
    k2_dft_h <<< 512, 512, 0, stream>>>(O);
    k3_mix   <<< 256, 512, 0, stream>>>(O);
    k4_idft_h<<< 256, 512, 0, stream>>>(O);
    k5_idft_w<<<1024, 256, 0, stream>>>(bias, O);
}

// Round 5
// 346.069 us; speedup vs baseline: 3.3368x; 1.2498x over previous
//
#include <hip/hip_runtime.h>
#include <math.h>

#define NB 16
#define NH 256
#define NW 256
#define NCIN 64
#define NCOUT 64
#define REGSZ 16384                  // floats per (b,h) 64 KB region of d_out
#define TWO_PI 6.28318530717958647692f
#define FSCALE (1.0f/65536.0f)       // norm='forward' 1/(H*W)

// Region float map (region r = 64 KB slice (b*256+h) of d_out):
//   [    0, 4096)  G1[b][h][ky][i] interleaved     (K1 -> K2)
//   [ 4096, 8192)  regions b*256+[0,64):  X_ft slot (K2 -> K3)
//                  regions b*256+[64,128): out_ft   (K3 -> K4)
//   [ 8192,12288)  (unused scratch)
//   [12288,16384)  tmp[b][h][ky][o] interleaved    (K4 -> K5)
// K5: one wave per (b,h): loads all its tmp to regs, then overwrites own
// region [0,16384) with the final output.

// ---------------- K1: forward DFT over w (real -> 32 complex modes) ----------
__global__ __launch_bounds__(256) void k1_dft_w(const float* __restrict__ x,
                                                float* __restrict__ O) {
    int t = threadIdx.x;
    int wave = t >> 6, lane = t & 63;
    int i2 = lane & 31;              // channel pair: channels 2*i2, 2*i2+1
    int kh = lane >> 5;              // ky = kh*16 + kk
    int bh = blockIdx.x * 4 + wave;  // 0..4095
    __shared__ float2 tw[256];
    { float s, c; sincosf(TWO_PI * (float)t * (1.0f/256.0f), &s, &c);
      tw[t] = make_float2(c, s); }
    __syncthreads();

    const float* xr = x + (size_t)bh * (NW*NCIN) + 2*i2;
    float re[16][2], im[16][2];
#pragma unroll
    for (int kk = 0; kk < 16; ++kk) {
        re[kk][0]=re[kk][1]=im[kk][0]=im[kk][1]=0.f;
    }

    for (int j = 1; j < 64; ++j) {
        float2 xa = *(const float2*)(xr + j*64);          // w=j
        float2 xb = *(const float2*)(xr + (256-j)*64);    // w=256-j
        float2 xc = *(const float2*)(xr + (64+j)*64);     // w=64+j
        float2 xd = *(const float2*)(xr + (192-j)*64);    // w=192-j
        float a0x = xa.x + xb.x, a0y = xa.y + xb.y;
        float d0x = xa.x - xb.x, d0y = xa.y - xb.y;
        float a1x = xc.x + xd.x, a1y = xc.y + xd.y;
        float d1x = xc.x - xd.x, d1y = xc.y - xd.y;
#pragma unroll
        for (int kk = 0; kk < 16; ++kk) {
            int p = ((kh*16 + kk) * j) & 255;
            float2 cs = tw[p];
            float C = cs.x, S = cs.y;
            re[kk][0] = fmaf(a0x, C, re[kk][0]);
            re[kk][1] = fmaf(a0y, C, re[kk][1]);
            im[kk][0] = fmaf(-d0x, S, im[kk][0]);
            im[kk][1] = fmaf(-d0y, S, im[kk][1]);
            if ((kk & 3) == 0) {        // cos=C, sin=S
                re[kk][0] = fmaf(a1x, C, re[kk][0]);
                re[kk][1] = fmaf(a1y, C, re[kk][1]);
                im[kk][0] = fmaf(-d1x, S, im[kk][0]);
                im[kk][1] = fmaf(-d1y, S, im[kk][1]);
            } else if ((kk & 3) == 1) { // cos=-S, sin=C
                re[kk][0] = fmaf(-a1x, S, re[kk][0]);
                re[kk][1] = fmaf(-a1y, S, re[kk][1]);
                im[kk][0] = fmaf(-d1x, C, im[kk][0]);
                im[kk][1] = fmaf(-d1y, C, im[kk][1]);
            } else if ((kk & 3) == 2) { // cos=-C, sin=-S
                re[kk][0] = fmaf(-a1x, C, re[kk][0]);
                re[kk][1] = fmaf(-a1y, C, re[kk][1]);
                im[kk][0] = fmaf(d1x, S, im[kk][0]);
                im[kk][1] = fmaf(d1y, S, im[kk][1]);
            } else {                    // cos=S, sin=-C
                re[kk][0] = fmaf(a1x, S, re[kk][0]);
                re[kk][1] = fmaf(a1y, S, re[kk][1]);
                im[kk][0] = fmaf(d1x, C, im[kk][0]);
                im[kk][1] = fmaf(d1y, C, im[kk][1]);
            }
        }
    }
    float2 e0   = *(const float2*)(xr + 0);
    float2 e64  = *(const float2*)(xr + 64*64);
    float2 e128 = *(const float2*)(xr + 128*64);
    float2 e192 = *(const float2*)(xr + 192*64);
    float a64x = e64.x + e192.x, a64y = e64.y + e192.y;
    float d64x = e64.x - e192.x, d64y = e64.y - e192.y;
#pragma unroll
    for (int kk = 0; kk < 16; ++kk) {
        re[kk][0] += e0.x; re[kk][1] += e0.y;
        if (kk & 1) { re[kk][0] -= e128.x; re[kk][1] -= e128.y; }
        else        { re[kk][0] += e128.x; re[kk][1] += e128.y; }
        if ((kk & 3) == 0)      { re[kk][0] += a64x; re[kk][1] += a64y; }
        else if ((kk & 3) == 1) { im[kk][0] -= d64x; im[kk][1] -= d64y; }
        else if ((kk & 3) == 2) { re[kk][0] -= a64x; re[kk][1] -= a64y; }
        else                    { im[kk][0] += d64x; im[kk][1] += d64y; }
    }
    float* R = O + (size_t)bh * REGSZ;
#pragma unroll
    for (int kk = 0; kk < 16; ++kk) {
        int ky = kh*16 + kk;
        *(float4*)(R + 2*(ky*64 + 2*i2)) =
            make_float4(re[kk][0]*FSCALE, im[kk][0]*FSCALE,
                        re[kk][1]*FSCALE, im[kk][1]*FSCALE);
    }
}

// ---------------- K2: forward DFT over h (keep 64 kx modes, +/- symmetry) ----
// X[kx] = sum_h G[h] e^{-i th}. Pair h<->256-h: P=G+G', M=G-G'.
// A = sum P cos, B = sum M sin; X[kx]=A-iB, X[256-kx]=A+iB.
// Thread (i=lane, kg): slots q=0..3, m=kg*4+q; slot m: kx pair (m, 256-m)
// i.e. kxidx (m, 64-m). Slot 0 (kg==0,q==0): singles kx=0 and kx=224.
__global__ __launch_bounds__(512) void k2_dft_h(float* __restrict__ O) {
    int b  = blockIdx.x >> 5;
    int ky = blockIdx.x & 31;
    int t  = threadIdx.x;
    int i  = t & 63;
    int kg = t >> 6;                 // 0..7
    __shared__ float2 tw[256];
    if (t < 256) { float s, c; sincosf(TWO_PI * (float)t * (1.0f/256.0f), &s, &c);
                   tw[t] = make_float2(c, s); }
    __syncthreads();

    float Ar[4]={0,0,0,0}, Ai[4]={0,0,0,0};
    float Br[4]={0,0,0,0}, Bi[4]={0,0,0,0};
    float S0r = 0.f, S0i = 0.f;      // kx=0 accumulator (kg==0 only)
    const float* base = O + (size_t)(b*NH)*REGSZ + 2*(ky*64 + i);

    for (int j = 1; j < 64; ++j) {
        float2 g0 = *(const float2*)(base + (size_t)j*REGSZ);
        float2 g1 = *(const float2*)(base + (size_t)(256-j)*REGSZ);
        float2 g2 = *(const float2*)(base + (size_t)(64+j)*REGSZ);
        float2 g3 = *(const float2*)(base + (size_t)(192-j)*REGSZ);
        float P0r = g0.x + g1.x, P0i = g0.y + g1.y;
        float M0r = g0.x - g1.x, M0i = g0.y - g1.y;
        float P1r = g2.x + g3.x, P1i = g2.y + g3.y;
        float M1r = g2.x - g3.x, M1i = g2.y - g3.y;
#pragma unroll
        for (int q = 0; q < 4; ++q) {
            int m = kg*4 + q;
            if (kg == 0 && q == 0) {
                // kx=0: sum of all G
                float PSr = P0r + P1r, PSi = P0i + P1i;
                float MSr = M0r + M1r, MSi = M0i + M1i;
                S0r += PSr; S0i += PSi;
                // kx=224: 224*64 % 256 == 0 -> quad-2 rotation is identity
                float2 cs = tw[(224*j) & 255];
                Ar[0]=fmaf(PSr,cs.x,Ar[0]); Ai[0]=fmaf(PSi,cs.x,Ai[0]);
                Br[0]=fmaf(MSr,cs.y,Br[0]); Bi[0]=fmaf(MSi,cs.y,Bi[0]);
            } else {
                float2 cs = tw[(m*j) & 255];
                float C = cs.x, S = cs.y;
                Ar[q]=fmaf(P0r,C,Ar[q]); Ai[q]=fmaf(P0i,C,Ai[q]);
                Br[q]=fmaf(M0r,S,Br[q]); Bi[q]=fmaf(M0i,S,Bi[q]);
                // h-quad 2 (h=64+j): twiddle rotated by +pi/2 * (m&3) == q
                float C2, S2;
                if (q == 0)      { C2 = C;  S2 = S;  }
                else if (q == 1) { C2 = -S; S2 = C;  }
                else if (q == 2) { C2 = -C; S2 = -S; }
                else             { C2 = S;  S2 = -C; }
                Ar[q]=fmaf(P1r,C2,Ar[q]); Ai[q]=fmaf(P1i,C2,Ai[q]);
                Br[q]=fmaf(M1r,S2,Br[q]); Bi[q]=fmaf(M1i,S2,Bi[q]);
            }
        }
    }
    // edges h = 0, 64, 128, 192
    {
        float2 e0   = *(const float2*)(base + (size_t)0);
        float2 e64  = *(const float2*)(base + (size_t)64*REGSZ);
        float2 e128 = *(const float2*)(base + (size_t)128*REGSZ);
        float2 e192 = *(const float2*)(base + (size_t)192*REGSZ);
        float p64r = e64.x + e192.x, p64i = e64.y + e192.y;
        float m64r = e64.x - e192.x, m64i = e64.y - e192.y;
#pragma unroll
        for (int q = 0; q < 4; ++q) {
            if (kg == 0 && q == 0) {
                S0r += e0.x + e64.x + e128.x + e192.x;
                S0i += e0.y + e64.y + e128.y + e192.y;
                // kx=224: cos at h=0,64,128 all = 1 (224*{64,128} = 0 mod 256)
                Ar[0] += e0.x + e128.x + p64r;
                Ai[0] += e0.y + e128.y + p64i;
            } else {
                Ar[q] += e0.x; Ai[q] += e0.y;
                if ((q & 1) == 0) { Ar[q] += e128.x; Ai[q] += e128.y; }
                else              { Ar[q] -= e128.x; Ai[q] -= e128.y; }
                if (q == 0)      { Ar[q] += p64r; Ai[q] += p64i; }
                else if (q == 1) { Br[q] += m64r; Bi[q] += m64i; }
                else if (q == 2) { Ar[q] -= p64r; Ai[q] -= p64i; }
                else             { Br[q] -= m64r; Bi[q] -= m64i; }
            }
        }
    }
    // write X
#pragma unroll
    for (int q = 0; q < 4; ++q) {
        int m = kg*4 + q;
        if (kg == 0 && q == 0) {
            // kxidx 0 (kx=0)
            float* p0w = O + (size_t)(b*256 + ky)*REGSZ + 4096 + 2*i;
            *(float2*)p0w = make_float2(S0r, S0i);
            // kxidx 32 (kx=224)
            float* p32 = O + (size_t)(b*256 + 32 + ky)*REGSZ + 4096 + 2*i;
            *(float2*)p32 = make_float2(Ar[0] + Bi[0], Ai[0] - Br[0]);
        } else {
            int k1i = m;             // kxidx m (<32)
            int k2i = 64 - m;        // kxidx 33..63
            float* pa = O + (size_t)(b*256 + ky)*REGSZ + 4096 + 2*(k1i*64 + i);
            *(float2*)pa = make_float2(Ar[q] + Bi[q], Ai[q] - Br[q]);
            float* pb = O + (size_t)(b*256 + 32 + ky)*REGSZ + 4096
                          + 2*((k2i & 31)*64 + i);
            *(float2*)pb = make_float2(Ar[q] - Bi[q], Ai[q] + Br[q]);
        }
    }
}

// ---------------- K3: channel mixing, weights read directly ------------------
// block (kx, kyq): stage X for all 16 b (64 KB LDS); stream original-layout
// weights per 4-i tile into double-buffered LDS (coalesced 32B chunks),
// software-pipelined (1 barrier per tile).
__global__ __launch_bounds__(512) void k3_mix(const float* __restrict__ w1re,
                                              const float* __restrict__ w1im,
                                              const float* __restrict__ w2re,
                                              const float* __restrict__ w2im,
                                              float* __restrict__ O) {
    int kx  = blockIdx.x >> 2;       // 0..63
    int kyq = blockIdx.x & 3;        // ky = kyq*8 + kyl
    int t   = threadIdx.x;
    __shared__ float2 lx[8192];      // [b][ky8][i] = 64 KB
    __shared__ float  lw[2][2][4][576];  // [buf][re/im][i4][o*9+ky8] = 36 KB
    const float* wre = (kx < 32) ? w1re : w2re;
    const float* wim = (kx < 32) ? w1im : w2im;
    int m    = kx & 31;
    int koff = (kx >> 5) << 5;
    // stage X
    for (int n = t; n < 8192; n += 512) {
        int bb = n >> 9, ky8 = (n >> 6) & 7, ii = n & 63;
        lx[n] = *(const float2*)(O + (size_t)(bb*256 + koff + kyq*8 + ky8)*REGSZ
                                   + 4096 + 2*(m*64 + ii));
    }
    // staging roles
    int sarr = t & 1, so = (t >> 1) & 63, si4 = t >> 7;
    const float* wsrc = sarr ? wim : wre;
    size_t sbase = (size_t)m*32 + kyq*8;
    // compute roles
    int kyl = t >> 6;                // 0..7
    int o   = t & 63;
    int kyg = kyq*8 + kyl;
    float ar[16], ai[16];
#pragma unroll
    for (int bb = 0; bb < 16; ++bb) { ar[bb] = 0.f; ai[bb] = 0.f; }

    // prologue: tile 0 into buf 0
    float4 wa, wb;
    {
        const float* src = wsrc + ((size_t)(si4*64 + so)*1024 + sbase);
        wa = *(const float4*)src; wb = *(const float4*)(src + 4);
        float* dst = &lw[0][sarr][si4][so*9];
        dst[0]=wa.x; dst[1]=wa.y; dst[2]=wa.z; dst[3]=wa.w;
        dst[4]=wb.x; dst[5]=wb.y; dst[6]=wb.z; dst[7]=wb.w;
    }
    __syncthreads();

    for (int k = 0; k < 16; ++k) {
        int i0 = k*4;
        float4 na, nb;
        if (k < 15) {   // issue next tile's loads early (hide under compute)
            const float* src = wsrc + ((size_t)((i0+4+si4)*64 + so)*1024 + sbase);
            na = *(const float4*)src; nb = *(const float4*)(src + 4);
        }
#pragma unroll
        for (int di = 0; di < 4; ++di) {
            float wr = lw[k & 1][0][di][o*9 + kyl];
            float wi = lw[k & 1][1][di][o*9 + kyl];
            int ii = i0 + di;
#pragma unroll
            for (int bb = 0; bb < 16; ++bb) {
                float2 xv = lx[(bb*8 + kyl)*64 + ii];
                ar[bb] = fmaf(xv.x, wr, fmaf(-xv.y, wi, ar[bb]));
                ai[bb] = fmaf(xv.x, wi, fmaf( xv.y, wr, ai[bb]));
            }
        }
        if (k < 15) {
            float* dst = &lw[(k+1) & 1][sarr][si4][so*9];
            dst[0]=na.x; dst[1]=na.y; dst[2]=na.z; dst[3]=na.w;
            dst[4]=nb.x; dst[5]=nb.y; dst[6]=nb.z; dst[7]=nb.w;
        }
        __syncthreads();
    }
#pragma unroll
    for (int bb = 0; bb < 16; ++bb) {
        float* cp = O + (size_t)(bb*256 + 64 + kx)*REGSZ + 4096 + 2*(kyg*64 + o);
        *(float2*)cp = make_float2(ar[bb], ai[bb]);
    }
}

// ---------------- K4: inverse DFT over h (+/- symmetry) ----------------------
// tmp[h] = sum_kx of[kx] e^{+i th}. Pair kx<->256-kx (kxidx m <-> 64-m):
// P = ofA+ofB, M = ofA-ofB; A = sum P cos, Bv = sum M sin;
// tmp[h] = (A.re - Bv.im, A.im + Bv.re), tmp[256-h] = (A.re + Bv.im, A.im - Bv.re).
// Singles kxidx 0 (kx=0) and 32 (kx=224) enter with P=M=of.
// block (b, hg, half): h-leads h0..h0+7 (0..127); hg==0 also does h=128.
__global__ __launch_bounds__(512) void k4_idft_h(float* __restrict__ O) {
    int b    = blockIdx.x >> 5;      // 0..15
    int hg   = (blockIdx.x >> 1) & 15;
    int half = blockIdx.x & 1;
    int t    = threadIdx.x;
    __shared__ float2 tw[256];
    if (t < 256) { float s, c; sincosf(TWO_PI * (float)t * (1.0f/256.0f), &s, &c);
                   tw[t] = make_float2(c, s); }
    __syncthreads();
    int ofs = half*2048 + t*4;       // float offset into 4096-float chunk
    int h0  = hg*8;
    float Are[8][2], Aim[8][2], Bre[8][2], Bim[8][2];
#pragma unroll
    for (int hh = 0; hh < 8; ++hh) {
        Are[hh][0]=Are[hh][1]=Aim[hh][0]=Aim[hh][1]=0.f;
        Bre[hh][0]=Bre[hh][1]=Bim[hh][0]=Bim[hh][1]=0.f;
    }
    const float* obase = O + 4096 + ofs;
    // singles
    float4 of0  = *(const float4*)(obase + (size_t)(b*256 + 64 +  0)*REGSZ);
    float4 of32 = *(const float4*)(obase + (size_t)(b*256 + 64 + 32)*REGSZ);
    float A128r0, A128i0, A128r1, A128i1;
    A128r0 = of0.x + of32.x; A128i0 = of0.y + of32.y;   // cos=1 for both @h=128
    A128r1 = of0.z + of32.z; A128i1 = of0.w + of32.w;
#pragma unroll
    for (int hh = 0; hh < 8; ++hh) {
        int h = h0 + hh;
        // kx=0: c=1, s=0
        Are[hh][0] += of0.x; Aim[hh][0] += of0.y;
        Are[hh][1] += of0.z; Aim[hh][1] += of0.w;
        // kx=224: P=M=of32
        float2 cs = tw[(224*h) & 255];
        Are[hh][0]=fmaf(of32.x,cs.x,Are[hh][0]); Aim[hh][0]=fmaf(of32.y,cs.x,Aim[hh][0]);
        Are[hh][1]=fmaf(of32.z,cs.x,Are[hh][1]); Aim[hh][1]=fmaf(of32.w,cs.x,Aim[hh][1]);
        Bre[hh][0]=fmaf(of32.x,cs.y,Bre[hh][0]); Bim[hh][0]=fmaf(of32.y,cs.y,Bim[hh][0]);
        Bre[hh][1]=fmaf(of32.z,cs.y,Bre[hh][1]); Bim[hh][1]=fmaf(of32.w,cs.y,Bim[hh][1]);
    }
    for (int mm = 1; mm < 32; ++mm) {
        float4 oa = *(const float4*)(obase + (size_t)(b*256 + 64 + mm)*REGSZ);
        float4 ob = *(const float4*)(obase + (size_t)(b*256 + 64 + (64-mm))*REGSZ);
        float Pr0 = oa.x + ob.x, Pi0 = oa.y + ob.y;
        float Pr1 = oa.z + ob.z, Pi1 = oa.w + ob.w;
        float Mr0 = oa.x - ob.x, Mi0 = oa.y - ob.y;
        float Mr1 = oa.z - ob.z, Mi1 = oa.w - ob.w;
#pragma unroll
        for (int hh = 0; hh < 8; ++hh) {
            float2 cs = tw[(mm*(h0+hh)) & 255];
            float C = cs.x, S = cs.y;
            Are[hh][0]=fmaf(Pr0,C,Are[hh][0]); Aim[hh][0]=fmaf(Pi0,C,Aim[hh][0]);
            Are[hh][1]=fmaf(Pr1,C,Are[hh][1]); Aim[hh][1]=fmaf(Pi1,C,Aim[hh][1]);
            Bre[hh][0]=fmaf(Mr0,S,Bre[hh][0]); Bim[hh][0]=fmaf(Mi0,S,Bim[hh][0]);
            Bre[hh][1]=fmaf(Mr1,S,Bre[hh][1]); Bim[hh][1]=fmaf(Mi1,S,Bim[hh][1]);
        }
        if (hg == 0) {               // h=128: c = (-1)^m, s = 0
            float sg = (mm & 1) ? -1.f : 1.f;
            A128r0 = fmaf(sg, Pr0, A128r0); A128i0 = fmaf(sg, Pi0, A128i0);
            A128r1 = fmaf(sg, Pr1, A128r1); A128i1 = fmaf(sg, Pi1, A128i1);
        }
    }
#pragma unroll
    for (int hh = 0; hh < 8; ++hh) {
        int h = h0 + hh;
        float* dp = O + (size_t)(b*256 + h)*REGSZ + 12288 + ofs;
        *(float4*)dp = make_float4(Are[hh][0]-Bim[hh][0], Aim[hh][0]+Bre[hh][0],
                                   Are[hh][1]-Bim[hh][1], Aim[hh][1]+Bre[hh][1]);
        if (h > 0) {
            float* dq = O + (size_t)(b*256 + 256 - h)*REGSZ + 12288 + ofs;
            *(float4*)dq = make_float4(Are[hh][0]+Bim[hh][0], Aim[hh][0]-Bre[hh][0],
                                       Are[hh][1]+Bim[hh][1], Aim[hh][1]-Bre[hh][1]);
        }
    }
    if (hg == 0) {
        float* dp = O + (size_t)(b*256 + 128)*REGSZ + 12288 + ofs;
        *(float4*)dp = make_float4(A128r0, A128i0, A128r1, A128i1);
    }
}

// ---------------- K5: inverse rfft over w + bias ----------------------------
__global__ __launch_bounds__(256) void k5_idft_w(const float* __restrict__ bias,
                                                 float* __restrict__ O) {
    int t = threadIdx.x;
    int wave = t >> 6, lane = t & 63;
    int o2 = lane & 31;              // channels 2*o2, 2*o2+1
    int kh = lane >> 5;
    int bh = blockIdx.x * 4 + wave;
    __shared__ float2 tw[256];
    { float s, c; sincosf(TWO_PI * (float)t * (1.0f/256.0f), &s, &c);
      tw[t] = make_float2(c, s); }
    __syncthreads();

    float* R = O + (size_t)bh * REGSZ;
    float2 bv = *(const float2*)(bias + 2*o2);
    float trr[16][2], tii[16][2];
#pragma unroll
    for (int kk = 0; kk < 16; ++kk) {
        int ky = kh*16 + kk;
        float4 v = *(const float4*)(R + 12288 + 2*(ky*64 + 2*o2));
        float sc = 2.f;
        if (kk == 0) sc = (kh == 0) ? 1.f : 2.f;
        trr[kk][0] = v.x*sc; tii[kk][0] = v.y*sc;
        trr[kk][1] = v.z*sc; tii[kk][1] = v.w*sc;
    }
    float A[2]={0,0}, Bc[2]={0,0}, P1[2]={0,0}, P2[2]={0,0};
#pragma unroll
    for (int kk = 0; kk < 16; ++kk) {
#pragma unroll
        for (int c = 0; c < 2; ++c) {
            A[c] += trr[kk][c];
            Bc[c] += (kk & 1) ? -trr[kk][c] : trr[kk][c];
            if ((kk & 3) == 0) P1[c] += trr[kk][c];
            else if ((kk & 3) == 2) P1[c] -= trr[kk][c];
            else if ((kk & 3) == 1) P2[c] += tii[kk][c];
            else P2[c] -= tii[kk][c];
        }
    }
#pragma unroll
    for (int c = 0; c < 2; ++c) {
        A[c]  += __shfl_xor(A[c], 32, 64);
        Bc[c] += __shfl_xor(Bc[c], 32, 64);
        P1[c] += __shfl_xor(P1[c], 32, 64);
        P2[c] += __shfl_xor(P2[c], 32, 64);
    }
    if (kh == 0) {
        *(float2*)(R + 0*64   + 2*o2) = make_float2(bv.x + A[0],  bv.y + A[1]);
        *(float2*)(R + 64*64  + 2*o2) = make_float2(bv.x + P1[0] - P2[0],
                                                    bv.y + P1[1] - P2[1]);
    } else {
        *(float2*)(R + 128*64 + 2*o2) = make_float2(bv.x + Bc[0], bv.y + Bc[1]);
        *(float2*)(R + 192*64 + 2*o2) = make_float2(bv.x + P1[0] + P2[0],
                                                    bv.y + P1[1] + P2[1]);
    }

    for (int j = 1; j < 64; ++j) {
        float E0[2]={0,0}, Od0[2]={0,0}, E1[2]={0,0}, Od1[2]={0,0};
#pragma unroll
        for (int kk = 0; kk < 16; ++kk) {
            int p = ((kh*16 + kk) * j) & 255;
            float2 cs = tw[p];
            float C = cs.x, S = cs.y;
            E0[0] = fmaf(trr[kk][0], C, E0[0]);
            E0[1] = fmaf(trr[kk][1], C, E0[1]);
            Od0[0] = fmaf(tii[kk][0], S, Od0[0]);
            Od0[1] = fmaf(tii[kk][1], S, Od0[1]);
            if ((kk & 3) == 0) {        // cos=C, sin=S
                E1[0] = fmaf(trr[kk][0], C, E1[0]);
                E1[1] = fmaf(trr[kk][1], C, E1[1]);
                Od1[0] = fmaf(tii[kk][0], S, Od1[0]);
                Od1[1] = fmaf(tii[kk][1], S, Od1[1]);
            } else if ((kk & 3) == 1) { // cos=-S, sin=C
                E1[0] = fmaf(-trr[kk][0], S, E1[0]);
                E1[1] = fmaf(-trr[kk][1], S, E1[1]);
                Od1[0] = fmaf(tii[kk][0], C, Od1[0]);
                Od1[1] = fmaf(tii[kk][1], C, Od1[1]);
            } else if ((kk & 3) == 2) { // cos=-C, sin=-S
                E1[0] = fmaf(-trr[kk][0], C, E1[0]);
                E1[1] = fmaf(-trr[kk][1], C, E1[1]);
                Od1[0] = fmaf(-tii[kk][0], S, Od1[0]);
                Od1[1] = fmaf(-tii[kk][1], S, Od1[1]);
            } else {                    // cos=S, sin=-C
                E1[0] = fmaf(trr[kk][0], S, E1[0]);
                E1[1] = fmaf(trr[kk][1], S, E1[1]);
                Od1[0] = fmaf(-tii[kk][0], C, Od1[0]);
                Od1[1] = fmaf(-tii[kk][1], C, Od1[1]);
            }
        }
#pragma unroll
        for (int c = 0; c < 2; ++c) {
            E0[c]  += __shfl_xor(E0[c], 32, 64);
            Od0[c] += __shfl_xor(Od0[c], 32, 64);
            E1[c]  += __shfl_xor(E1[c], 32, 64);
            Od1[c] += __shfl_xor(Od1[c], 32, 64);
        }
        if (kh == 0) {
            *(float2*)(R + j*64 + 2*o2) =
                make_float2(bv.x + E0[0] - Od0[0], bv.y + E0[1] - Od0[1]);
            *(float2*)(R + (64+j)*64 + 2*o2) =
                make_float2(bv.x + E1[0] - Od1[0], bv.y + E1[1] - Od1[1]);
        } else {
            *(float2*)(R + (256-j)*64 + 2*o2) =
                make_float2(bv.x + E0[0] + Od0[0], bv.y + E0[1] + Od0[1]);
            *(float2*)(R + (192-j)*64 + 2*o2) =
                make_float2(bv.x + E1[0] + Od1[0], bv.y + E1[1] + Od1[1]);
        }
    }
}

extern "C" void kernel_launch(void* const* d_in, const int* in_sizes, int n_in,
                              void* d_out, int out_size, void* d_ws, size_t ws_size,
                              hipStream_t stream) {
    (void)in_sizes; (void)n_in; (void)d_ws; (void)ws_size; (void)out_size;
    const float* x    = (const float*)d_in[0];
    const float* w1re = (const float*)d_in[1];
    const float* w1im = (const float*)d_in[2];
    const float* w2re = (const float*)d_in[3];
    const float* w2im = (const float*)d_in[4];
    const float* bias = (const float*)d_in[5];
    float* O = (float*)d_out;

    k1_dft_w <<<1024, 256, 0, stream>>>(x, O);
    k2_dft_h <<< 512, 512, 0, stream>>>(O);
    k3_mix   <<< 256, 512, 0, stream>>>(w1re, w1im, w2re, w2im, O);
    k4_idft_h<<< 512, 512, 0, stream>>>(O);
    k5_idft_w<<<1024, 256, 0, stream>>>(bias, O);
}